// Round 11
// baseline (362.920 us; speedup 1.0000x reference)
//
#include <hip/hip_runtime.h>

// R11: out_gemm K-SPLIT (80-segment balanced grid, atomicAdd partials into
// zeroed out, seg0 carries bias) — same critical-path fix that won in s1(R10).
// Own zero2 kernel replaces hipMemsetAsync (ambiguous 58us fill). cvt3 and
// projqk launch fusions (ws is ~402MB per poison-fill evidence). Rest = R10.

#define L_SEQ 2048
#define NBATCH 4
#define DMODEL 1024
#define NHEAD 8
#define SCALING 0.08838834764831845f
#define NQ (2048L * 4 * 1024)

typedef _Float16 f16x8 __attribute__((ext_vector_type(8)));
typedef float f32x4 __attribute__((ext_vector_type(4)));

#define GLOBAL_AS __attribute__((address_space(1)))
#define LDS_AS __attribute__((address_space(3)))

__device__ __forceinline__ unsigned short f2h_bits(float x) {
  _Float16 h = (_Float16)x;
  return __builtin_bit_cast(unsigned short, h);
}

__device__ __forceinline__ void gl_lds16(const void* g, void* l) {
  __builtin_amdgcn_global_load_lds((GLOBAL_AS void*)g, (LDS_AS void*)l, 16, 0, 0);
}

// ---------------------------------------------------------------------------
// zero2: zero out-region (n4a float4s) + Zsum (n4b float4s), grid-stride.
// ---------------------------------------------------------------------------
__global__ __launch_bounds__(256) void zero2(
    float4* __restrict__ a, long n4a, float4* __restrict__ b, long n4b)
{
  float4 z = {0.f, 0.f, 0.f, 0.f};
  long stride = (long)gridDim.x * 256;
  for (long i = (long)blockIdx.x * 256 + threadIdx.x; i < n4a; i += stride)
    a[i] = z;
  for (long i = (long)blockIdx.x * 256 + threadIdx.x; i < n4b; i += stride)
    b[i] = z;
}

// ---------------------------------------------------------------------------
// cvt3: f32 -> f16 for q,k,v in one launch (dst = xh + which*NQ).
// ---------------------------------------------------------------------------
__global__ __launch_bounds__(256) void cvt3(
    const float* __restrict__ q, const float* __restrict__ k,
    const float* __restrict__ v, _Float16* __restrict__ xh)
{
  long i = ((long)blockIdx.x * 256 + threadIdx.x) * 8;
  if (i >= 3 * NQ) return;
  int which = (int)(i / NQ);
  const float* src = which == 0 ? q : (which == 1 ? k : v);
  long off = i - (long)which * NQ;
  float4 a = *(const float4*)(src + off);
  float4 b = *(const float4*)(src + off + 4);
  f16x8 h;
  h[0] = (_Float16)a.x; h[1] = (_Float16)a.y; h[2] = (_Float16)a.z; h[3] = (_Float16)a.w;
  h[4] = (_Float16)b.x; h[5] = (_Float16)b.y; h[6] = (_Float16)b.z; h[7] = (_Float16)b.w;
  *(f16x8*)(xh + i) = h;
}

// ---------------------------------------------------------------------------
// gemm16: 128x128 tile. Retained for the small Wvo prep GEMM only.
// ---------------------------------------------------------------------------
template <bool AF16, bool BF16>
__global__ __launch_bounds__(256) void gemm16(
    const void* __restrict__ Ap, long lda, long a_bs,
    const void* __restrict__ Bp, long ldb, long b_bs,
    float* __restrict__ C, long ldc, long c_bs,
    _Float16* __restrict__ Ch, long ldch, long ch_bs,
    const float* __restrict__ bias, int bias_row, float alpha, int K,
    int causal, int cmode)
{
  __shared__ __align__(16) _Float16 As[128][64];
  __shared__ __align__(16) _Float16 Bs[128][64];
  const int tid = threadIdx.x;
  const int lane = tid & 63, wv = tid >> 6;
  const int g = lane >> 4, cc = lane & 15;
  const int wm = wv >> 1, wn = wv & 1;
  const long m0 = (long)blockIdx.y * 128;
  const long n0 = (long)blockIdx.x * 128;

  const float* Af = nullptr; const _Float16* Ah = nullptr;
  const float* Bf = nullptr; const _Float16* Bh = nullptr;
  if constexpr (AF16) Ah = (const _Float16*)Ap + (long)blockIdx.z * a_bs;
  else                Af = (const float*)Ap + (long)blockIdx.z * a_bs;
  if constexpr (BF16) Bh = (const _Float16*)Bp + (long)blockIdx.z * b_bs;
  else                Bf = (const float*)Bp + (long)blockIdx.z * b_bs;

  int Keff = K;
  if (causal) { int lim = (int)m0 + 128; if (lim < K) Keff = lim; }
  const int NT = Keff >> 6;

  f32x4 acc[4][4] = {};
  char* AsB = (char*)&As[0][0];
  char* BsB = (char*)&Bs[0][0];

  for (int kt = 0; kt < NT; ++kt) {
    const long k0 = (long)kt << 6;
    __syncthreads();
    if constexpr (AF16) {
#pragma unroll
      for (int i = 0; i < 4; ++i) {
        int r = 32 * wv + 8 * i + (lane >> 3);
        int gc = (lane & 7) ^ (r & 7);
        gl_lds16(Ah + (m0 + r) * lda + k0 + gc * 8, &As[32 * wv + 8 * i][0]);
      }
    } else {
#pragma unroll
      for (int p = 0; p < 8; ++p) {
        int r = p * 16 + (tid >> 4);
        float4 vv = *(const float4*)(Af + (m0 + r) * lda + k0 + (tid & 15) * 4);
        ushort4 hh;
        hh.x = f2h_bits(vv.x); hh.y = f2h_bits(vv.y);
        hh.z = f2h_bits(vv.z); hh.w = f2h_bits(vv.w);
        *(ushort4*)(AsB + r * 128 + (((tid & 15) * 8) ^ ((r & 7) << 4))) = hh;
      }
    }
    if constexpr (BF16) {
#pragma unroll
      for (int i = 0; i < 4; ++i) {
        int r = 32 * wv + 8 * i + (lane >> 3);
        int gc = (lane & 7) ^ (r & 7);
        gl_lds16(Bh + (n0 + r) * ldb + k0 + gc * 8, &Bs[32 * wv + 8 * i][0]);
      }
    } else {
#pragma unroll
      for (int p = 0; p < 8; ++p) {
        int r = p * 16 + (tid >> 4);
        float4 vv = *(const float4*)(Bf + (n0 + r) * ldb + k0 + (tid & 15) * 4);
        ushort4 hh;
        hh.x = f2h_bits(vv.x); hh.y = f2h_bits(vv.y);
        hh.z = f2h_bits(vv.z); hh.w = f2h_bits(vv.w);
        *(ushort4*)(BsB + r * 128 + (((tid & 15) * 8) ^ ((r & 7) << 4))) = hh;
      }
    }
    __syncthreads();
#pragma unroll
    for (int s = 0; s < 2; ++s) {
      f16x8 af[4], bfr[4];
#pragma unroll
      for (int mi = 0; mi < 4; ++mi) {
        int r = wm * 64 + mi * 16 + cc;
        af[mi] = *(const f16x8*)(AsB + r * 128 + ((s * 64 + 16 * g) ^ ((r & 7) << 4)));
      }
#pragma unroll
      for (int ni = 0; ni < 4; ++ni) {
        int r = wn * 64 + ni * 16 + cc;
        bfr[ni] = *(const f16x8*)(BsB + r * 128 + ((s * 64 + 16 * g) ^ ((r & 7) << 4)));
      }
#pragma unroll
      for (int mi = 0; mi < 4; ++mi)
#pragma unroll
        for (int ni = 0; ni < 4; ++ni)
          acc[mi][ni] = __builtin_amdgcn_mfma_f32_16x16x32_f16(af[mi], bfr[ni], acc[mi][ni], 0, 0, 0);
    }
  }

  float* Cp = C ? C + (long)blockIdx.z * c_bs : nullptr;
  _Float16* Chp = Ch ? Ch + (long)blockIdx.z * ch_bs : nullptr;
#pragma unroll
  for (int ni = 0; ni < 4; ++ni) {
    long col = n0 + wn * 64 + ni * 16 + cc;
    float bcol = (bias && !bias_row) ? bias[col] : 0.0f;
#pragma unroll
    for (int mi = 0; mi < 4; ++mi) {
      long row0 = m0 + wm * 64 + mi * 16 + 4 * g;
#pragma unroll
      for (int rg = 0; rg < 4; ++rg) {
        long row = row0 + rg;
        float b = (bias && bias_row) ? bias[row] : bcol;
        float vv = (acc[mi][ni][rg] + b) * alpha;
        if (Cp) Cp[row * ldc + col] = vv;
        if (Chp) {
          if (cmode == 1) {
            long idx = (((row & 3) * NHEAD + (col >> 7)) * (long)L_SEQ + (row >> 2)) * 128 +
                       (col & 127);
            Chp[idx] = (_Float16)vv;
          } else {
            Chp[row * ldch + col] = (_Float16)vv;
          }
        }
      }
    }
  }
}

// ---------------------------------------------------------------------------
// projqk: q and k projections in one launch (blockIdx.y selects). 64x128
// tiles, all-f16 dual gl_lds staging, head-major store. ntiles=8.
// ---------------------------------------------------------------------------
__global__ __launch_bounds__(256) void projqk(
    const _Float16* __restrict__ xh, const _Float16* __restrict__ WqT,
    const _Float16* __restrict__ WkT, const float* __restrict__ bq,
    const float* __restrict__ bk, _Float16* __restrict__ qph,
    _Float16* __restrict__ kph)
{
  __shared__ __align__(16) _Float16 As[64][64];
  __shared__ __align__(16) _Float16 Bs[128][64];
  const int tid = threadIdx.x, lane = tid & 63, wv = tid >> 6;
  const int g = lane >> 4, cc = lane & 15;
  const int wm = wv >> 1, wn = wv & 1;
  const int sel = (int)blockIdx.y;
  const _Float16* A = xh + (long)sel * NQ;
  const _Float16* B = sel ? WkT : WqT;
  const float* bias = sel ? bk : bq;
  const float alpha = sel ? 1.0f : SCALING;
  _Float16* dst = sel ? kph : qph;
  const int fi = (int)blockIdx.x;
  const long m0 = (long)(fi >> 3) * 64;
  const long n0 = (long)(fi & 7) * 128;

  f32x4 acc[2][4] = {};
  char* AsB = (char*)&As[0][0];
  char* BsB = (char*)&Bs[0][0];

  for (int kt = 0; kt < 16; ++kt) {
    const long k0 = (long)kt << 6;
    __syncthreads();
#pragma unroll
    for (int i = 0; i < 2; ++i) {
      int r = 16 * wv + 8 * i + (lane >> 3);
      int gc = (lane & 7) ^ (r & 7);
      gl_lds16(A + (m0 + r) * 1024 + k0 + gc * 8, &As[16 * wv + 8 * i][0]);
    }
#pragma unroll
    for (int i = 0; i < 4; ++i) {
      int r = 32 * wv + 8 * i + (lane >> 3);
      int gc = (lane & 7) ^ (r & 7);
      gl_lds16(B + (n0 + r) * 1024 + k0 + gc * 8, &Bs[32 * wv + 8 * i][0]);
    }
    __syncthreads();
#pragma unroll
    for (int s = 0; s < 2; ++s) {
      f16x8 af[2], bfr[4];
#pragma unroll
      for (int mi = 0; mi < 2; ++mi) {
        int r = wm * 32 + mi * 16 + cc;
        af[mi] = *(const f16x8*)(AsB + r * 128 + ((s * 64 + 16 * g) ^ ((r & 7) << 4)));
      }
#pragma unroll
      for (int ni = 0; ni < 4; ++ni) {
        int r = wn * 64 + ni * 16 + cc;
        bfr[ni] = *(const f16x8*)(BsB + r * 128 + ((s * 64 + 16 * g) ^ ((r & 7) << 4)));
      }
#pragma unroll
      for (int mi = 0; mi < 2; ++mi)
#pragma unroll
        for (int ni = 0; ni < 4; ++ni)
          acc[mi][ni] = __builtin_amdgcn_mfma_f32_16x16x32_f16(af[mi], bfr[ni], acc[mi][ni], 0, 0, 0);
    }
  }

#pragma unroll
  for (int ni = 0; ni < 4; ++ni) {
    long col = n0 + wn * 64 + ni * 16 + cc;
    float bcol = bias[col];
#pragma unroll
    for (int mi = 0; mi < 2; ++mi) {
      long row0 = m0 + wm * 32 + mi * 16 + 4 * g;
#pragma unroll
      for (int rg = 0; rg < 4; ++rg) {
        long row = row0 + rg;
        float vv = (acc[mi][ni][rg] + bcol) * alpha;
        long idx = (((row & 3) * NHEAD + (col >> 7)) * (long)L_SEQ + (row >> 2)) * 128 +
                   (col & 127);
        dst[idx] = (_Float16)vv;
      }
    }
  }
}

// ---------------------------------------------------------------------------
// proj64 (R8): 64x128 tile, all-f16 dual gl_lds staging. Used for voT.
// ---------------------------------------------------------------------------
__global__ __launch_bounds__(256) void proj64(
    const _Float16* __restrict__ Ap, long lda, long a_bs,
    const _Float16* __restrict__ Bp, long ldb, long b_bs,
    _Float16* __restrict__ Ch, long ldch, long ch_bs,
    const float* __restrict__ bias, int bias_row, float alpha, int K,
    int cmode, int ntiles)
{
  __shared__ __align__(16) _Float16 As[64][64];
  __shared__ __align__(16) _Float16 Bs[128][64];
  const int tid = threadIdx.x, lane = tid & 63, wv = tid >> 6;
  const int g = lane >> 4, cc = lane & 15;
  const int wm = wv >> 1, wn = wv & 1;
  const int fi = (int)blockIdx.x;
  const int by = fi / ntiles, nc = fi % ntiles;
  const long m0 = (long)by * 64;
  const long n0 = (long)nc * 128;
  const _Float16* A = Ap + (long)blockIdx.z * a_bs;
  const _Float16* B = Bp + (long)blockIdx.z * b_bs;
  const int NT = K >> 6;

  f32x4 acc[2][4] = {};
  char* AsB = (char*)&As[0][0];
  char* BsB = (char*)&Bs[0][0];

  for (int kt = 0; kt < NT; ++kt) {
    const long k0 = (long)kt << 6;
    __syncthreads();
#pragma unroll
    for (int i = 0; i < 2; ++i) {
      int r = 16 * wv + 8 * i + (lane >> 3);
      int gc = (lane & 7) ^ (r & 7);
      gl_lds16(A + (m0 + r) * lda + k0 + gc * 8, &As[16 * wv + 8 * i][0]);
    }
#pragma unroll
    for (int i = 0; i < 4; ++i) {
      int r = 32 * wv + 8 * i + (lane >> 3);
      int gc = (lane & 7) ^ (r & 7);
      gl_lds16(B + (n0 + r) * ldb + k0 + gc * 8, &Bs[32 * wv + 8 * i][0]);
    }
    __syncthreads();
#pragma unroll
    for (int s = 0; s < 2; ++s) {
      f16x8 af[2], bfr[4];
#pragma unroll
      for (int mi = 0; mi < 2; ++mi) {
        int r = wm * 32 + mi * 16 + cc;
        af[mi] = *(const f16x8*)(AsB + r * 128 + ((s * 64 + 16 * g) ^ ((r & 7) << 4)));
      }
#pragma unroll
      for (int ni = 0; ni < 4; ++ni) {
        int r = wn * 64 + ni * 16 + cc;
        bfr[ni] = *(const f16x8*)(BsB + r * 128 + ((s * 64 + 16 * g) ^ ((r & 7) << 4)));
      }
#pragma unroll
      for (int mi = 0; mi < 2; ++mi)
#pragma unroll
        for (int ni = 0; ni < 4; ++ni)
          acc[mi][ni] = __builtin_amdgcn_mfma_f32_16x16x32_f16(af[mi], bfr[ni], acc[mi][ni], 0, 0, 0);
    }
  }

  _Float16* Chp = Ch + (long)blockIdx.z * ch_bs;
#pragma unroll
  for (int ni = 0; ni < 4; ++ni) {
    long col = n0 + wn * 64 + ni * 16 + cc;
    float bcol = bias_row ? 0.0f : bias[col];
#pragma unroll
    for (int mi = 0; mi < 2; ++mi) {
      long row0 = m0 + wm * 32 + mi * 16 + 4 * g;
#pragma unroll
      for (int rg = 0; rg < 4; ++rg) {
        long row = row0 + rg;
        float b = bias_row ? bias[row] : bcol;
        float vv = (acc[mi][ni][rg] + b) * alpha;
        if (cmode == 1) {
          long idx = (((row & 3) * NHEAD + (col >> 7)) * (long)L_SEQ + (row >> 2)) * 128 +
                     (col & 127);
          Chp[idx] = (_Float16)vv;
        } else {
          Chp[row * ldch + col] = (_Float16)vv;
        }
      }
    }
  }
}

// ---------------------------------------------------------------------------
// out_split: out += partial(wmean @ voT^T), K-split into 80 balanced segments
// (<=8 chunks each, same decode as s1). seg0 adds bias. atomicAdd into the
// pre-zeroed out. Grid (80, 8 col-tiles, 4 batch).
// ---------------------------------------------------------------------------
__global__ __launch_bounds__(256) void out_split(
    const float* __restrict__ wmean, const _Float16* __restrict__ voT,
    const float* __restrict__ bo, float* __restrict__ out)
{
  __shared__ __align__(16) _Float16 As[64][64];
  __shared__ __align__(16) _Float16 Bs[128][64];
  const int tid = threadIdx.x, lane = tid & 63, wv = tid >> 6;
  const int g = lane >> 4, cc = lane & 15;
  const int wm = wv >> 1, wn = wv & 1;
  int fi = 79 - (int)blockIdx.x;
  int by, seg;
  if (fi < 8)       { by = fi;                  seg = 0; }
  else if (fi < 24) { int t = fi - 8;  by = 8  + (t >> 1); seg = t & 1; }
  else if (fi < 48) { int t = fi - 24; by = 16 + t / 3;    seg = t % 3; }
  else              { int t = fi - 48; by = 24 + (t >> 2); seg = t & 3; }
  const int nc = (int)blockIdx.y, nb = (int)blockIdx.z;
  const long m0 = (long)by * 64;
  const long n0 = (long)nc * 128;
  const int c0 = seg * 8;
  const int cEnd = min(c0 + 8, by + 1);
  const float* A = wmean + (long)nb * L_SEQ * L_SEQ;
  const _Float16* B = voT + (long)nb * 2048L * 1024;

  f32x4 acc[2][4] = {};
  char* AsB = (char*)&As[0][0];
  char* BsB = (char*)&Bs[0][0];

  for (int kt = c0; kt < cEnd; ++kt) {
    const long k0 = (long)kt << 6;
    __syncthreads();
#pragma unroll
    for (int p = 0; p < 4; ++p) {
      int r = p * 16 + (tid >> 4);
      float4 vv = *(const float4*)(A + (m0 + r) * 2048 + k0 + (tid & 15) * 4);
      ushort4 hh;
      hh.x = f2h_bits(vv.x); hh.y = f2h_bits(vv.y);
      hh.z = f2h_bits(vv.z); hh.w = f2h_bits(vv.w);
      *(ushort4*)(AsB + r * 128 + (((tid & 15) * 8) ^ ((r & 7) << 4))) = hh;
    }
#pragma unroll
    for (int i = 0; i < 4; ++i) {
      int r = 32 * wv + 8 * i + (lane >> 3);
      int gc = (lane & 7) ^ (r & 7);
      gl_lds16(B + (n0 + r) * 2048 + k0 + gc * 8, &Bs[32 * wv + 8 * i][0]);
    }
    __syncthreads();
#pragma unroll
    for (int s = 0; s < 2; ++s) {
      f16x8 af[2], bfr[4];
#pragma unroll
      for (int mi = 0; mi < 2; ++mi) {
        int r = wm * 32 + mi * 16 + cc;
        af[mi] = *(const f16x8*)(AsB + r * 128 + ((s * 64 + 16 * g) ^ ((r & 7) << 4)));
      }
#pragma unroll
      for (int ni = 0; ni < 4; ++ni) {
        int r = wn * 64 + ni * 16 + cc;
        bfr[ni] = *(const f16x8*)(BsB + r * 128 + ((s * 64 + 16 * g) ^ ((r & 7) << 4)));
      }
#pragma unroll
      for (int mi = 0; mi < 2; ++mi)
#pragma unroll
        for (int ni = 0; ni < 4; ++ni)
          acc[mi][ni] = __builtin_amdgcn_mfma_f32_16x16x32_f16(af[mi], bfr[ni], acc[mi][ni], 0, 0, 0);
    }
  }

#pragma unroll
  for (int ni = 0; ni < 4; ++ni) {
    long col = n0 + wn * 64 + ni * 16 + cc;
    float b = (seg == 0) ? bo[col] : 0.0f;
#pragma unroll
    for (int mi = 0; mi < 2; ++mi) {
      long l0 = m0 + wm * 32 + mi * 16 + 4 * g;
#pragma unroll
      for (int rg = 0; rg < 4; ++rg)
        atomicAdd(&out[(l0 + rg) * 4096 + nb * 1024 + col], acc[mi][ni][rg] + b);
    }
  }
}

// ---------------------------------------------------------------------------
__global__ __launch_bounds__(256) void transpose3(
    const float* __restrict__ s0, const float* __restrict__ s1,
    const float* __restrict__ s2,
    _Float16* __restrict__ d0, _Float16* __restrict__ d1,
    _Float16* __restrict__ d2)
{
  __shared__ _Float16 tile[32][33];
  const float* in = blockIdx.z == 0 ? s0 : (blockIdx.z == 1 ? s1 : s2);
  _Float16* outp = blockIdx.z == 0 ? d0 : (blockIdx.z == 1 ? d1 : d2);
  int r0 = blockIdx.y * 32, c0 = blockIdx.x * 32;
  for (int i = threadIdx.y; i < 32; i += 8)
    tile[i][threadIdx.x] = (_Float16)in[(long)(r0 + i) * 1024 + c0 + threadIdx.x];
  __syncthreads();
  for (int i = threadIdx.y; i < 32; i += 8)
    outp[(long)(c0 + i) * 1024 + r0 + threadIdx.x] = tile[threadIdx.x][i];
}

__global__ __launch_bounds__(256) void bias_proj(
    const float* __restrict__ bv, const float* __restrict__ Wo, float* __restrict__ bvo)
{
  int j = blockIdx.x * 256 + threadIdx.x;
  float acc = 0.f;
  for (int i = 0; i < DMODEL; ++i) acc += bv[i] * Wo[(long)i * DMODEL + j];
  bvo[j] = acc;
}

// ---------------------------------------------------------------------------
// S1 (R10, proven): K-split partial Zsum via atomicAdd. 80-segment grid.
// ---------------------------------------------------------------------------
__global__ __launch_bounds__(256) void s1_kernel(
    const _Float16* __restrict__ qph, const _Float16* __restrict__ kph,
    float* __restrict__ Zsum)
{
  __shared__ __align__(16) _Float16 Qs[64][128];
  __shared__ __align__(16) _Float16 Ks[64][128];
  const int tid = threadIdx.x, lane = tid & 63, w = tid >> 6;
  const int g = lane >> 4, cc = lane & 15;
  const int h = blockIdx.y, nb = blockIdx.z;
  int fi = 79 - (int)blockIdx.x;
  int by, seg;
  if (fi < 8)       { by = fi;                  seg = 0; }
  else if (fi < 24) { int t = fi - 8;  by = 8  + (t >> 1); seg = t & 1; }
  else if (fi < 48) { int t = fi - 24; by = 16 + t / 3;    seg = t % 3; }
  else              { int t = fi - 48; by = 24 + (t >> 2); seg = t & 3; }
  const int lb = by * 64;
  const int c0 = seg * 8;
  const int cEnd = min(c0 + 8, by + 1);
  const int srow = lane >> 4, scl = lane & 15;
  const long hb = ((long)(nb * NHEAD + h)) * L_SEQ * 128;
  char* QsB = (char*)&Qs[0][0];
  char* KsB = (char*)&Ks[0][0];

#pragma unroll
  for (int i = 0; i < 4; ++i) {
    int r = 16 * w + 4 * i + srow;
    int gc = scl ^ (r & 7);
    gl_lds16(&qph[hb + (long)(lb + r) * 128 + gc * 8], &Qs[16 * w + 4 * i][0]);
  }
  auto stageK = [&](int ch) {
#pragma unroll
    for (int i = 0; i < 4; ++i) {
      int r = 16 * w + 4 * i + srow;
      int gc = scl ^ (r & 7);
      gl_lds16(&kph[hb + (long)(ch * 64 + r) * 128 + gc * 8], &Ks[16 * w + 4 * i][0]);
    }
  };
  stageK(c0);
  __syncthreads();

  f16x8 qf[4];
  {
    int r = 16 * w + cc;
#pragma unroll
    for (int s = 0; s < 4; ++s)
      qf[s] = *(const f16x8*)(QsB + r * 256 + ((64 * s + 16 * g) ^ ((r & 7) << 4)));
  }

  f32x4 zacc = {0.f, 0.f, 0.f, 0.f};
  const int l0 = lb + 16 * w + 4 * g;
  for (int ch = c0; ch < cEnd; ++ch) {
#pragma unroll
    for (int t = 0; t < 4; ++t) {
      int kr = 16 * t + cc;
      f32x4 acc = {0.f, 0.f, 0.f, 0.f};
#pragma unroll
      for (int s = 0; s < 4; ++s) {
        f16x8 kf = *(const f16x8*)(KsB + kr * 256 + ((64 * s + 16 * g) ^ ((kr & 7) << 4)));
        acc = __builtin_amdgcn_mfma_f32_16x16x32_f16(qf[s], kf, acc, 0, 0, 0);
      }
      int m = ch * 64 + 16 * t + cc;
#pragma unroll
      for (int rg = 0; rg < 4; ++rg) {
        float e = __expf(acc[rg]);
        zacc[rg] += (m <= l0 + rg) ? e : 0.f;
      }
    }
    if (ch + 1 < cEnd) {
      __syncthreads();
      stageK(ch + 1);
      __syncthreads();
    }
  }
#pragma unroll
  for (int rg = 0; rg < 4; ++rg) {
    float vv = zacc[rg];
    vv += __shfl_xor(vv, 1, 16);
    vv += __shfl_xor(vv, 2, 16);
    vv += __shfl_xor(vv, 4, 16);
    vv += __shfl_xor(vv, 8, 16);
    if (cc == 0)
      atomicAdd(&Zsum[((long)nb * NHEAD + h) * L_SEQ + l0 + rg], vv);
  }
}

// ---------------------------------------------------------------------------
__global__ __launch_bounds__(256) void zero_fill(float* __restrict__ wmean)
{
  int t = (int)blockIdx.x, nb = (int)blockIdx.y;
  int by = 0, rem = t;
  while (rem >= 15 - by) { rem -= 15 - by; ++by; }
  const int mc = by + 1 + rem;
  const int tr = threadIdx.x >> 1, th = threadIdx.x & 1;
  float4 z4 = {0.f, 0.f, 0.f, 0.f};
  float* p = wmean + (long)nb * L_SEQ * L_SEQ + (long)(by * 128 + tr) * L_SEQ +
             mc * 128 + th * 64;
#pragma unroll
  for (int j = 0; j < 16; ++j) ((float4*)p)[j] = z4;
}

// ---------------------------------------------------------------------------
// S2 (R10, proven): 64x64 triangle tiles, zl = 1/(8*Zsum) at load.
// ---------------------------------------------------------------------------
__global__ __launch_bounds__(256) void s2_kernel(
    const _Float16* __restrict__ qph, const _Float16* __restrict__ kph,
    const float* __restrict__ Zsum, float* __restrict__ wmean)
{
  __shared__ __align__(16) _Float16 Qs[64][128];
  __shared__ __align__(16) _Float16 Ks[64][128];
  __shared__ float zl[NHEAD][64];
  const int tid = threadIdx.x, lane = tid & 63, w = tid >> 6;
  const int g = lane >> 4, cc = lane & 15;
  const int nb = blockIdx.y;
  int b = (int)blockIdx.x;
  int bx = (b & 7) * 66 + (b >> 3);          // XCD swizzle (528 = 8*66)
  int by = 0, rem = bx;
  while (rem > by) { rem -= by + 1; ++by; }
  const int mc = rem;
  const int lb = by * 64, mb = mc * 64;
  const bool diag = (mc == by);
  const int srow = lane >> 4, scl = lane & 15;
  char* QsB = (char*)&Qs[0][0];
  char* KsB = (char*)&Ks[0][0];

  for (int i = tid; i < NHEAD * 64; i += 256)
    zl[i >> 6][i & 63] =
        1.0f / (8.0f * Zsum[((long)nb * NHEAD + (i >> 6)) * L_SEQ + lb + (i & 63)]);

  auto stage = [&](int h) {
    const long qb = ((long)(nb * NHEAD + h) * L_SEQ + lb) * 128;
    const long kb = ((long)(nb * NHEAD + h) * L_SEQ + mb) * 128;
#pragma unroll
    for (int i = 0; i < 4; ++i) {
      int r = 16 * w + 4 * i + srow;
      int gc = scl ^ (r & 7);
      gl_lds16(&qph[qb + (long)r * 128 + gc * 8], &Qs[16 * w + 4 * i][0]);
      gl_lds16(&kph[kb + (long)r * 128 + gc * 8], &Ks[16 * w + 4 * i][0]);
    }
  };
  stage(0);
  __syncthreads();

  f32x4 wacc[4] = {};
  const int l0 = lb + 16 * w + 4 * g;
  for (int h = 0; h < NHEAD; ++h) {
    f16x8 qf[4];
    int qr = 16 * w + cc;
#pragma unroll
    for (int s = 0; s < 4; ++s)
      qf[s] = *(const f16x8*)(QsB + qr * 256 + ((64 * s + 16 * g) ^ ((qr & 7) << 4)));
    f32x4 zv = *(const f32x4*)&zl[h][16 * w + 4 * g];
#pragma unroll
    for (int t = 0; t < 4; ++t) {
      int kr = 16 * t + cc;
      f32x4 acc = {0.f, 0.f, 0.f, 0.f};
#pragma unroll
      for (int s = 0; s < 4; ++s) {
        f16x8 kf = *(const f16x8*)(KsB + kr * 256 + ((64 * s + 16 * g) ^ ((kr & 7) << 4)));
        acc = __builtin_amdgcn_mfma_f32_16x16x32_f16(qf[s], kf, acc, 0, 0, 0);
      }
      int m = mb + 16 * t + cc;
#pragma unroll
      for (int rg = 0; rg < 4; ++rg) {
        float e = __expf(acc[rg]) * zv[rg];
        wacc[t][rg] += (!diag || m <= l0 + rg) ? e : 0.f;
      }
    }
    if (h + 1 < NHEAD) {
      __syncthreads();
      stage(h + 1);
      __syncthreads();
    }
  }
  float* wout = wmean + (long)nb * L_SEQ * L_SEQ;
#pragma unroll
  for (int t = 0; t < 4; ++t) {
    int m = mb + 16 * t + cc;
#pragma unroll
    for (int rg = 0; rg < 4; ++rg)
      wout[(long)(l0 + rg) * L_SEQ + m] = wacc[t][rg];
  }
}

// ---------------------------------------------------------------------------
extern "C" void kernel_launch(void* const* d_in, const int* in_sizes, int n_in,
                              void* d_out, int out_size, void* d_ws, size_t ws_size,
                              hipStream_t stream)
{
  const float* q  = (const float*)d_in[0];
  const float* k  = (const float*)d_in[1];
  const float* v  = (const float*)d_in[2];
  const float* Wq = (const float*)d_in[3];
  const float* bq = (const float*)d_in[4];
  const float* Wk = (const float*)d_in[5];
  const float* bk = (const float*)d_in[6];
  const float* Wv = (const float*)d_in[7];
  const float* bv = (const float*)d_in[8];
  const float* Wo = (const float*)d_in[9];
  const float* bo = (const float*)d_in[10];

  float* out = (float*)d_out;
  float* wmean = out + (long)L_SEQ * NBATCH * DMODEL;

  if (ws_size < (106UL << 20)) return;

  char* ws = (char*)d_ws;
  _Float16* xh   = (_Float16*)(ws);                   // 48 MB (q,k,v f16)
  _Float16* qph  = (_Float16*)(ws + (48L << 20));     // 16 MB head-major
  _Float16* kph  = (_Float16*)(ws + (64L << 20));     // 16 MB head-major
  _Float16* voT  = (_Float16*)(ws + (80L << 20));     // 16 MB
  _Float16* WqT  = (_Float16*)(ws + (96L << 20));     // 2 MB
  _Float16* WkT  = (_Float16*)(ws + (98L << 20));     // 2 MB
  _Float16* WoT  = (_Float16*)(ws + (100L << 20));    // 2 MB
  _Float16* WvoT = (_Float16*)(ws + (102L << 20));    // 2 MB
  float*    bvo  = (float*)   (ws + (104L << 20));    // 4 KB
  float*    Zsum = (float*)   (ws + (104L << 20) + (1L << 16));  // 256 KB

  // zero out-region (atomic target) + Zsum
  zero2<<<dim3(1024, 1, 1), 256, 0, stream>>>(
      (float4*)out, NQ / 4, (float4*)Zsum, (long)NBATCH * NHEAD * L_SEQ / 4);
  transpose3<<<dim3(32, 32, 3), dim3(32, 8, 1), 0, stream>>>(
      Wq, Wk, Wo, WqT, WkT, WoT);
  bias_proj<<<dim3(4, 1, 1), 256, 0, stream>>>(bv, Wo, bvo);
  gemm16<true, false><<<dim3(8, 8, 1), 256, 0, stream>>>(
      WoT, 1024, 0, Wv, 1024, 0,
      (float*)nullptr, 0, 0, WvoT, 1024, 0,
      (const float*)nullptr, 0, 1.0f, 1024, 0, 0);
  // f32->f16 for q,k,v in one launch
  cvt3<<<dim3(12288, 1, 1), 256, 0, stream>>>(q, k, v, xh);
  // q & k projections fused (head-major out)
  projqk<<<dim3(1024, 2, 1), 256, 0, stream>>>(xh, WqT, WkT, bq, bk, qph, kph);
  // voT[nb][d][m] = sum_c WvoT[d][c] * vh[m*4+nb][c] + bvo[d]
  proj64<<<dim3(256, 1, 4), 256, 0, stream>>>(
      WvoT, 1024, 0, xh + 2 * NQ, 4096, 1024, voT, 2048, 2048L * 1024,
      bvo, 1, 1.0f, 1024, 0, 16);
  // Softmax stats (K-split), upper zeros, head-avg weights
  s1_kernel<<<dim3(80, NHEAD, NBATCH), 256, 0, stream>>>(qph, kph, Zsum);
  zero_fill<<<dim3(120, 4, 1), 256, 0, stream>>>(wmean);
  s2_kernel<<<dim3(528, NBATCH, 1), 256, 0, stream>>>(qph, kph, Zsum, wmean);
  // out = wmean @ voT^T + bo, K-split with atomic accumulation
  out_split<<<dim3(80, 8, 4), 256, 0, stream>>>(wmean, voT, bo, out);
}

// Round 12
// 332.398 us; speedup vs baseline: 1.0918x; 1.0918x over previous
//
#include <hip/hip_runtime.h>

// R12: revert out to R5's out_gemm (atomics in out_split cost +36us: 21M f32
// atomicAdds serialize at L2 — K-split only pays when partial output is tiny,
// as in s1). Keep R11's fusions (zero2[Zsum-only], cvt3, projqk) which netted
// ~-21us. Everything else = R10/R11 proven configs.

#define L_SEQ 2048
#define NBATCH 4
#define DMODEL 1024
#define NHEAD 8
#define SCALING 0.08838834764831845f
#define NQ (2048L * 4 * 1024)

typedef _Float16 f16x8 __attribute__((ext_vector_type(8)));
typedef float f32x4 __attribute__((ext_vector_type(4)));

#define GLOBAL_AS __attribute__((address_space(1)))
#define LDS_AS __attribute__((address_space(3)))

__device__ __forceinline__ unsigned short f2h_bits(float x) {
  _Float16 h = (_Float16)x;
  return __builtin_bit_cast(unsigned short, h);
}

__device__ __forceinline__ void gl_lds16(const void* g, void* l) {
  __builtin_amdgcn_global_load_lds((GLOBAL_AS void*)g, (LDS_AS void*)l, 16, 0, 0);
}

// ---------------------------------------------------------------------------
// zero1: zero Zsum (grid-stride float4).
// ---------------------------------------------------------------------------
__global__ __launch_bounds__(256) void zero1(float4* __restrict__ a, long n4)
{
  float4 z = {0.f, 0.f, 0.f, 0.f};
  long stride = (long)gridDim.x * 256;
  for (long i = (long)blockIdx.x * 256 + threadIdx.x; i < n4; i += stride)
    a[i] = z;
}

// ---------------------------------------------------------------------------
// cvt3: f32 -> f16 for q,k,v in one launch (dst = xh + which*NQ).
// ---------------------------------------------------------------------------
__global__ __launch_bounds__(256) void cvt3(
    const float* __restrict__ q, const float* __restrict__ k,
    const float* __restrict__ v, _Float16* __restrict__ xh)
{
  long i = ((long)blockIdx.x * 256 + threadIdx.x) * 8;
  if (i >= 3 * NQ) return;
  int which = (int)(i / NQ);
  const float* src = which == 0 ? q : (which == 1 ? k : v);
  long off = i - (long)which * NQ;
  float4 a = *(const float4*)(src + off);
  float4 b = *(const float4*)(src + off + 4);
  f16x8 h;
  h[0] = (_Float16)a.x; h[1] = (_Float16)a.y; h[2] = (_Float16)a.z; h[3] = (_Float16)a.w;
  h[4] = (_Float16)b.x; h[5] = (_Float16)b.y; h[6] = (_Float16)b.z; h[7] = (_Float16)b.w;
  *(f16x8*)(xh + i) = h;
}

// ---------------------------------------------------------------------------
// gemm16: 128x128 tile. Retained for the small Wvo prep GEMM only.
// ---------------------------------------------------------------------------
template <bool AF16, bool BF16>
__global__ __launch_bounds__(256) void gemm16(
    const void* __restrict__ Ap, long lda, long a_bs,
    const void* __restrict__ Bp, long ldb, long b_bs,
    float* __restrict__ C, long ldc, long c_bs,
    _Float16* __restrict__ Ch, long ldch, long ch_bs,
    const float* __restrict__ bias, int bias_row, float alpha, int K,
    int causal, int cmode)
{
  __shared__ __align__(16) _Float16 As[128][64];
  __shared__ __align__(16) _Float16 Bs[128][64];
  const int tid = threadIdx.x;
  const int lane = tid & 63, wv = tid >> 6;
  const int g = lane >> 4, cc = lane & 15;
  const int wm = wv >> 1, wn = wv & 1;
  const long m0 = (long)blockIdx.y * 128;
  const long n0 = (long)blockIdx.x * 128;

  const float* Af = nullptr; const _Float16* Ah = nullptr;
  const float* Bf = nullptr; const _Float16* Bh = nullptr;
  if constexpr (AF16) Ah = (const _Float16*)Ap + (long)blockIdx.z * a_bs;
  else                Af = (const float*)Ap + (long)blockIdx.z * a_bs;
  if constexpr (BF16) Bh = (const _Float16*)Bp + (long)blockIdx.z * b_bs;
  else                Bf = (const float*)Bp + (long)blockIdx.z * b_bs;

  int Keff = K;
  if (causal) { int lim = (int)m0 + 128; if (lim < K) Keff = lim; }
  const int NT = Keff >> 6;

  f32x4 acc[4][4] = {};
  char* AsB = (char*)&As[0][0];
  char* BsB = (char*)&Bs[0][0];

  for (int kt = 0; kt < NT; ++kt) {
    const long k0 = (long)kt << 6;
    __syncthreads();
    if constexpr (AF16) {
#pragma unroll
      for (int i = 0; i < 4; ++i) {
        int r = 32 * wv + 8 * i + (lane >> 3);
        int gc = (lane & 7) ^ (r & 7);
        gl_lds16(Ah + (m0 + r) * lda + k0 + gc * 8, &As[32 * wv + 8 * i][0]);
      }
    } else {
#pragma unroll
      for (int p = 0; p < 8; ++p) {
        int r = p * 16 + (tid >> 4);
        float4 vv = *(const float4*)(Af + (m0 + r) * lda + k0 + (tid & 15) * 4);
        ushort4 hh;
        hh.x = f2h_bits(vv.x); hh.y = f2h_bits(vv.y);
        hh.z = f2h_bits(vv.z); hh.w = f2h_bits(vv.w);
        *(ushort4*)(AsB + r * 128 + (((tid & 15) * 8) ^ ((r & 7) << 4))) = hh;
      }
    }
    if constexpr (BF16) {
#pragma unroll
      for (int i = 0; i < 4; ++i) {
        int r = 32 * wv + 8 * i + (lane >> 3);
        int gc = (lane & 7) ^ (r & 7);
        gl_lds16(Bh + (n0 + r) * ldb + k0 + gc * 8, &Bs[32 * wv + 8 * i][0]);
      }
    } else {
#pragma unroll
      for (int p = 0; p < 8; ++p) {
        int r = p * 16 + (tid >> 4);
        float4 vv = *(const float4*)(Bf + (n0 + r) * ldb + k0 + (tid & 15) * 4);
        ushort4 hh;
        hh.x = f2h_bits(vv.x); hh.y = f2h_bits(vv.y);
        hh.z = f2h_bits(vv.z); hh.w = f2h_bits(vv.w);
        *(ushort4*)(BsB + r * 128 + (((tid & 15) * 8) ^ ((r & 7) << 4))) = hh;
      }
    }
    __syncthreads();
#pragma unroll
    for (int s = 0; s < 2; ++s) {
      f16x8 af[4], bfr[4];
#pragma unroll
      for (int mi = 0; mi < 4; ++mi) {
        int r = wm * 64 + mi * 16 + cc;
        af[mi] = *(const f16x8*)(AsB + r * 128 + ((s * 64 + 16 * g) ^ ((r & 7) << 4)));
      }
#pragma unroll
      for (int ni = 0; ni < 4; ++ni) {
        int r = wn * 64 + ni * 16 + cc;
        bfr[ni] = *(const f16x8*)(BsB + r * 128 + ((s * 64 + 16 * g) ^ ((r & 7) << 4)));
      }
#pragma unroll
      for (int mi = 0; mi < 4; ++mi)
#pragma unroll
        for (int ni = 0; ni < 4; ++ni)
          acc[mi][ni] = __builtin_amdgcn_mfma_f32_16x16x32_f16(af[mi], bfr[ni], acc[mi][ni], 0, 0, 0);
    }
  }

  float* Cp = C ? C + (long)blockIdx.z * c_bs : nullptr;
  _Float16* Chp = Ch ? Ch + (long)blockIdx.z * ch_bs : nullptr;
#pragma unroll
  for (int ni = 0; ni < 4; ++ni) {
    long col = n0 + wn * 64 + ni * 16 + cc;
    float bcol = (bias && !bias_row) ? bias[col] : 0.0f;
#pragma unroll
    for (int mi = 0; mi < 4; ++mi) {
      long row0 = m0 + wm * 64 + mi * 16 + 4 * g;
#pragma unroll
      for (int rg = 0; rg < 4; ++rg) {
        long row = row0 + rg;
        float b = (bias && bias_row) ? bias[row] : bcol;
        float vv = (acc[mi][ni][rg] + b) * alpha;
        if (Cp) Cp[row * ldc + col] = vv;
        if (Chp) {
          if (cmode == 1) {
            long idx = (((row & 3) * NHEAD + (col >> 7)) * (long)L_SEQ + (row >> 2)) * 128 +
                       (col & 127);
            Chp[idx] = (_Float16)vv;
          } else {
            Chp[row * ldch + col] = (_Float16)vv;
          }
        }
      }
    }
  }
}

// ---------------------------------------------------------------------------
// projqk (R11, kept): q and k projections in one launch (blockIdx.y selects).
// ---------------------------------------------------------------------------
__global__ __launch_bounds__(256) void projqk(
    const _Float16* __restrict__ xh, const _Float16* __restrict__ WqT,
    const _Float16* __restrict__ WkT, const float* __restrict__ bq,
    const float* __restrict__ bk, _Float16* __restrict__ qph,
    _Float16* __restrict__ kph)
{
  __shared__ __align__(16) _Float16 As[64][64];
  __shared__ __align__(16) _Float16 Bs[128][64];
  const int tid = threadIdx.x, lane = tid & 63, wv = tid >> 6;
  const int g = lane >> 4, cc = lane & 15;
  const int wm = wv >> 1, wn = wv & 1;
  const int sel = (int)blockIdx.y;
  const _Float16* A = xh + (long)sel * NQ;
  const _Float16* B = sel ? WkT : WqT;
  const float* bias = sel ? bk : bq;
  const float alpha = sel ? 1.0f : SCALING;
  _Float16* dst = sel ? kph : qph;
  const int fi = (int)blockIdx.x;
  const long m0 = (long)(fi >> 3) * 64;
  const long n0 = (long)(fi & 7) * 128;

  f32x4 acc[2][4] = {};
  char* AsB = (char*)&As[0][0];
  char* BsB = (char*)&Bs[0][0];

  for (int kt = 0; kt < 16; ++kt) {
    const long k0 = (long)kt << 6;
    __syncthreads();
#pragma unroll
    for (int i = 0; i < 2; ++i) {
      int r = 16 * wv + 8 * i + (lane >> 3);
      int gc = (lane & 7) ^ (r & 7);
      gl_lds16(A + (m0 + r) * 1024 + k0 + gc * 8, &As[16 * wv + 8 * i][0]);
    }
#pragma unroll
    for (int i = 0; i < 4; ++i) {
      int r = 32 * wv + 8 * i + (lane >> 3);
      int gc = (lane & 7) ^ (r & 7);
      gl_lds16(B + (n0 + r) * 1024 + k0 + gc * 8, &Bs[32 * wv + 8 * i][0]);
    }
    __syncthreads();
#pragma unroll
    for (int s = 0; s < 2; ++s) {
      f16x8 af[2], bfr[4];
#pragma unroll
      for (int mi = 0; mi < 2; ++mi) {
        int r = wm * 32 + mi * 16 + cc;
        af[mi] = *(const f16x8*)(AsB + r * 128 + ((s * 64 + 16 * g) ^ ((r & 7) << 4)));
      }
#pragma unroll
      for (int ni = 0; ni < 4; ++ni) {
        int r = wn * 64 + ni * 16 + cc;
        bfr[ni] = *(const f16x8*)(BsB + r * 128 + ((s * 64 + 16 * g) ^ ((r & 7) << 4)));
      }
#pragma unroll
      for (int mi = 0; mi < 2; ++mi)
#pragma unroll
        for (int ni = 0; ni < 4; ++ni)
          acc[mi][ni] = __builtin_amdgcn_mfma_f32_16x16x32_f16(af[mi], bfr[ni], acc[mi][ni], 0, 0, 0);
    }
  }

#pragma unroll
  for (int ni = 0; ni < 4; ++ni) {
    long col = n0 + wn * 64 + ni * 16 + cc;
    float bcol = bias[col];
#pragma unroll
    for (int mi = 0; mi < 2; ++mi) {
      long row0 = m0 + wm * 32 + mi * 16 + 4 * g;
#pragma unroll
      for (int rg = 0; rg < 4; ++rg) {
        long row = row0 + rg;
        float vv = (acc[mi][ni][rg] + bcol) * alpha;
        long idx = (((row & 3) * NHEAD + (col >> 7)) * (long)L_SEQ + (row >> 2)) * 128 +
                   (col & 127);
        dst[idx] = (_Float16)vv;
      }
    }
  }
}

// ---------------------------------------------------------------------------
// proj64 (R8): 64x128 tile, all-f16 dual gl_lds staging. Used for voT.
// ---------------------------------------------------------------------------
__global__ __launch_bounds__(256) void proj64(
    const _Float16* __restrict__ Ap, long lda, long a_bs,
    const _Float16* __restrict__ Bp, long ldb, long b_bs,
    _Float16* __restrict__ Ch, long ldch, long ch_bs,
    const float* __restrict__ bias, int bias_row, float alpha, int K,
    int cmode, int ntiles)
{
  __shared__ __align__(16) _Float16 As[64][64];
  __shared__ __align__(16) _Float16 Bs[128][64];
  const int tid = threadIdx.x, lane = tid & 63, wv = tid >> 6;
  const int g = lane >> 4, cc = lane & 15;
  const int wm = wv >> 1, wn = wv & 1;
  const int fi = (int)blockIdx.x;
  const int by = fi / ntiles, nc = fi % ntiles;
  const long m0 = (long)by * 64;
  const long n0 = (long)nc * 128;
  const _Float16* A = Ap + (long)blockIdx.z * a_bs;
  const _Float16* B = Bp + (long)blockIdx.z * b_bs;
  const int NT = K >> 6;

  f32x4 acc[2][4] = {};
  char* AsB = (char*)&As[0][0];
  char* BsB = (char*)&Bs[0][0];

  for (int kt = 0; kt < NT; ++kt) {
    const long k0 = (long)kt << 6;
    __syncthreads();
#pragma unroll
    for (int i = 0; i < 2; ++i) {
      int r = 16 * wv + 8 * i + (lane >> 3);
      int gc = (lane & 7) ^ (r & 7);
      gl_lds16(A + (m0 + r) * lda + k0 + gc * 8, &As[16 * wv + 8 * i][0]);
    }
#pragma unroll
    for (int i = 0; i < 4; ++i) {
      int r = 32 * wv + 8 * i + (lane >> 3);
      int gc = (lane & 7) ^ (r & 7);
      gl_lds16(B + (n0 + r) * ldb + k0 + gc * 8, &Bs[32 * wv + 8 * i][0]);
    }
    __syncthreads();
#pragma unroll
    for (int s = 0; s < 2; ++s) {
      f16x8 af[2], bfr[4];
#pragma unroll
      for (int mi = 0; mi < 2; ++mi) {
        int r = wm * 32 + mi * 16 + cc;
        af[mi] = *(const f16x8*)(AsB + r * 128 + ((s * 64 + 16 * g) ^ ((r & 7) << 4)));
      }
#pragma unroll
      for (int ni = 0; ni < 4; ++ni) {
        int r = wn * 64 + ni * 16 + cc;
        bfr[ni] = *(const f16x8*)(BsB + r * 128 + ((s * 64 + 16 * g) ^ ((r & 7) << 4)));
      }
#pragma unroll
      for (int mi = 0; mi < 2; ++mi)
#pragma unroll
        for (int ni = 0; ni < 4; ++ni)
          acc[mi][ni] = __builtin_amdgcn_mfma_f32_16x16x32_f16(af[mi], bfr[ni], acc[mi][ni], 0, 0, 0);
    }
  }

  _Float16* Chp = Ch + (long)blockIdx.z * ch_bs;
#pragma unroll
  for (int ni = 0; ni < 4; ++ni) {
    long col = n0 + wn * 64 + ni * 16 + cc;
    float bcol = bias_row ? 0.0f : bias[col];
#pragma unroll
    for (int mi = 0; mi < 2; ++mi) {
      long row0 = m0 + wm * 32 + mi * 16 + 4 * g;
#pragma unroll
      for (int rg = 0; rg < 4; ++rg) {
        long row = row0 + rg;
        float b = bias_row ? bias[row] : bcol;
        float vv = (acc[mi][ni][rg] + b) * alpha;
        if (cmode == 1) {
          long idx = (((row & 3) * NHEAD + (col >> 7)) * (long)L_SEQ + (row >> 2)) * 128 +
                     (col & 127);
          Chp[idx] = (_Float16)vv;
        } else {
          Chp[row * ldch + col] = (_Float16)vv;
        }
      }
    }
  }
}

// ---------------------------------------------------------------------------
// out_gemm (R5, proven): out = wmean @ voT^T + bo, causal. 64x128 tiles,
// 1024 blocks heavy-first, direct stores (no atomics).
// ---------------------------------------------------------------------------
__global__ __launch_bounds__(256) void out_gemm(
    const float* __restrict__ wmean, const _Float16* __restrict__ voT,
    const float* __restrict__ bo, float* __restrict__ out)
{
  __shared__ __align__(16) _Float16 As[64][64];
  __shared__ __align__(16) _Float16 Bs[128][64];
  const int tid = threadIdx.x, lane = tid & 63, wv = tid >> 6;
  const int g = lane >> 4, cc = lane & 15;
  const int wm = wv >> 1, wn = wv & 1;
  const int fi = (int)blockIdx.x;
  const int by = 31 - (fi >> 5);
  const int j = fi & 31;
  const int nb = j >> 3, nc = j & 7;
  const long m0 = (long)by * 64;
  const long n0 = (long)nc * 128;
  const float* A = wmean + (long)nb * L_SEQ * L_SEQ;
  const _Float16* B = voT + (long)nb * 2048L * 1024;
  const int NT = by + 1;

  f32x4 acc[2][4] = {};
  char* AsB = (char*)&As[0][0];
  char* BsB = (char*)&Bs[0][0];

  for (int kt = 0; kt < NT; ++kt) {
    const long k0 = (long)kt << 6;
    __syncthreads();
#pragma unroll
    for (int p = 0; p < 4; ++p) {
      int r = p * 16 + (tid >> 4);
      float4 vv = *(const float4*)(A + (m0 + r) * 2048 + k0 + (tid & 15) * 4);
      ushort4 hh;
      hh.x = f2h_bits(vv.x); hh.y = f2h_bits(vv.y);
      hh.z = f2h_bits(vv.z); hh.w = f2h_bits(vv.w);
      *(ushort4*)(AsB + r * 128 + (((tid & 15) * 8) ^ ((r & 7) << 4))) = hh;
    }
#pragma unroll
    for (int i = 0; i < 4; ++i) {
      int r = 32 * wv + 8 * i + (lane >> 3);
      int gc = (lane & 7) ^ (r & 7);
      gl_lds16(B + (n0 + r) * 2048 + k0 + gc * 8, &Bs[32 * wv + 8 * i][0]);
    }
    __syncthreads();
#pragma unroll
    for (int s = 0; s < 2; ++s) {
      f16x8 af[2], bfr[4];
#pragma unroll
      for (int mi = 0; mi < 2; ++mi) {
        int r = wm * 32 + mi * 16 + cc;
        af[mi] = *(const f16x8*)(AsB + r * 128 + ((s * 64 + 16 * g) ^ ((r & 7) << 4)));
      }
#pragma unroll
      for (int ni = 0; ni < 4; ++ni) {
        int r = wn * 64 + ni * 16 + cc;
        bfr[ni] = *(const f16x8*)(BsB + r * 128 + ((s * 64 + 16 * g) ^ ((r & 7) << 4)));
      }
#pragma unroll
      for (int mi = 0; mi < 2; ++mi)
#pragma unroll
        for (int ni = 0; ni < 4; ++ni)
          acc[mi][ni] = __builtin_amdgcn_mfma_f32_16x16x32_f16(af[mi], bfr[ni], acc[mi][ni], 0, 0, 0);
    }
  }

#pragma unroll
  for (int ni = 0; ni < 4; ++ni) {
    long col = n0 + wn * 64 + ni * 16 + cc;
    float b = bo[col];
#pragma unroll
    for (int mi = 0; mi < 2; ++mi) {
      long l0 = m0 + wm * 32 + mi * 16 + 4 * g;
#pragma unroll
      for (int rg = 0; rg < 4; ++rg)
        out[(l0 + rg) * 4096 + nb * 1024 + col] = acc[mi][ni][rg] + b;
    }
  }
}

// ---------------------------------------------------------------------------
__global__ __launch_bounds__(256) void transpose3(
    const float* __restrict__ s0, const float* __restrict__ s1,
    const float* __restrict__ s2,
    _Float16* __restrict__ d0, _Float16* __restrict__ d1,
    _Float16* __restrict__ d2)
{
  __shared__ _Float16 tile[32][33];
  const float* in = blockIdx.z == 0 ? s0 : (blockIdx.z == 1 ? s1 : s2);
  _Float16* outp = blockIdx.z == 0 ? d0 : (blockIdx.z == 1 ? d1 : d2);
  int r0 = blockIdx.y * 32, c0 = blockIdx.x * 32;
  for (int i = threadIdx.y; i < 32; i += 8)
    tile[i][threadIdx.x] = (_Float16)in[(long)(r0 + i) * 1024 + c0 + threadIdx.x];
  __syncthreads();
  for (int i = threadIdx.y; i < 32; i += 8)
    outp[(long)(c0 + i) * 1024 + r0 + threadIdx.x] = tile[threadIdx.x][i];
}

__global__ __launch_bounds__(256) void bias_proj(
    const float* __restrict__ bv, const float* __restrict__ Wo, float* __restrict__ bvo)
{
  int j = blockIdx.x * 256 + threadIdx.x;
  float acc = 0.f;
  for (int i = 0; i < DMODEL; ++i) acc += bv[i] * Wo[(long)i * DMODEL + j];
  bvo[j] = acc;
}

// ---------------------------------------------------------------------------
// S1 (R10, proven): K-split partial Zsum via atomicAdd. 80-segment grid.
// ---------------------------------------------------------------------------
__global__ __launch_bounds__(256) void s1_kernel(
    const _Float16* __restrict__ qph, const _Float16* __restrict__ kph,
    float* __restrict__ Zsum)
{
  __shared__ __align__(16) _Float16 Qs[64][128];
  __shared__ __align__(16) _Float16 Ks[64][128];
  const int tid = threadIdx.x, lane = tid & 63, w = tid >> 6;
  const int g = lane >> 4, cc = lane & 15;
  const int h = blockIdx.y, nb = blockIdx.z;
  int fi = 79 - (int)blockIdx.x;
  int by, seg;
  if (fi < 8)       { by = fi;                  seg = 0; }
  else if (fi < 24) { int t = fi - 8;  by = 8  + (t >> 1); seg = t & 1; }
  else if (fi < 48) { int t = fi - 24; by = 16 + t / 3;    seg = t % 3; }
  else              { int t = fi - 48; by = 24 + (t >> 2); seg = t & 3; }
  const int lb = by * 64;
  const int c0 = seg * 8;
  const int cEnd = min(c0 + 8, by + 1);
  const int srow = lane >> 4, scl = lane & 15;
  const long hb = ((long)(nb * NHEAD + h)) * L_SEQ * 128;
  char* QsB = (char*)&Qs[0][0];
  char* KsB = (char*)&Ks[0][0];

#pragma unroll
  for (int i = 0; i < 4; ++i) {
    int r = 16 * w + 4 * i + srow;
    int gc = scl ^ (r & 7);
    gl_lds16(&qph[hb + (long)(lb + r) * 128 + gc * 8], &Qs[16 * w + 4 * i][0]);
  }
  auto stageK = [&](int ch) {
#pragma unroll
    for (int i = 0; i < 4; ++i) {
      int r = 16 * w + 4 * i + srow;
      int gc = scl ^ (r & 7);
      gl_lds16(&kph[hb + (long)(ch * 64 + r) * 128 + gc * 8], &Ks[16 * w + 4 * i][0]);
    }
  };
  stageK(c0);
  __syncthreads();

  f16x8 qf[4];
  {
    int r = 16 * w + cc;
#pragma unroll
    for (int s = 0; s < 4; ++s)
      qf[s] = *(const f16x8*)(QsB + r * 256 + ((64 * s + 16 * g) ^ ((r & 7) << 4)));
  }

  f32x4 zacc = {0.f, 0.f, 0.f, 0.f};
  const int l0 = lb + 16 * w + 4 * g;
  for (int ch = c0; ch < cEnd; ++ch) {
#pragma unroll
    for (int t = 0; t < 4; ++t) {
      int kr = 16 * t + cc;
      f32x4 acc = {0.f, 0.f, 0.f, 0.f};
#pragma unroll
      for (int s = 0; s < 4; ++s) {
        f16x8 kf = *(const f16x8*)(KsB + kr * 256 + ((64 * s + 16 * g) ^ ((kr & 7) << 4)));
        acc = __builtin_amdgcn_mfma_f32_16x16x32_f16(qf[s], kf, acc, 0, 0, 0);
      }
      int m = ch * 64 + 16 * t + cc;
#pragma unroll
      for (int rg = 0; rg < 4; ++rg) {
        float e = __expf(acc[rg]);
        zacc[rg] += (m <= l0 + rg) ? e : 0.f;
      }
    }
    if (ch + 1 < cEnd) {
      __syncthreads();
      stageK(ch + 1);
      __syncthreads();
    }
  }
#pragma unroll
  for (int rg = 0; rg < 4; ++rg) {
    float vv = zacc[rg];
    vv += __shfl_xor(vv, 1, 16);
    vv += __shfl_xor(vv, 2, 16);
    vv += __shfl_xor(vv, 4, 16);
    vv += __shfl_xor(vv, 8, 16);
    if (cc == 0)
      atomicAdd(&Zsum[((long)nb * NHEAD + h) * L_SEQ + l0 + rg], vv);
  }
}

// ---------------------------------------------------------------------------
__global__ __launch_bounds__(256) void zero_fill(float* __restrict__ wmean)
{
  int t = (int)blockIdx.x, nb = (int)blockIdx.y;
  int by = 0, rem = t;
  while (rem >= 15 - by) { rem -= 15 - by; ++by; }
  const int mc = by + 1 + rem;
  const int tr = threadIdx.x >> 1, th = threadIdx.x & 1;
  float4 z4 = {0.f, 0.f, 0.f, 0.f};
  float* p = wmean + (long)nb * L_SEQ * L_SEQ + (long)(by * 128 + tr) * L_SEQ +
             mc * 128 + th * 64;
#pragma unroll
  for (int j = 0; j < 16; ++j) ((float4*)p)[j] = z4;
}

// ---------------------------------------------------------------------------
// S2 (R10, proven): 64x64 triangle tiles, zl = 1/(8*Zsum) at load.
// ---------------------------------------------------------------------------
__global__ __launch_bounds__(256) void s2_kernel(
    const _Float16* __restrict__ qph, const _Float16* __restrict__ kph,
    const float* __restrict__ Zsum, float* __restrict__ wmean)
{
  __shared__ __align__(16) _Float16 Qs[64][128];
  __shared__ __align__(16) _Float16 Ks[64][128];
  __shared__ float zl[NHEAD][64];
  const int tid = threadIdx.x, lane = tid & 63, w = tid >> 6;
  const int g = lane >> 4, cc = lane & 15;
  const int nb = blockIdx.y;
  int b = (int)blockIdx.x;
  int bx = (b & 7) * 66 + (b >> 3);          // XCD swizzle (528 = 8*66)
  int by = 0, rem = bx;
  while (rem > by) { rem -= by + 1; ++by; }
  const int mc = rem;
  const int lb = by * 64, mb = mc * 64;
  const bool diag = (mc == by);
  const int srow = lane >> 4, scl = lane & 15;
  char* QsB = (char*)&Qs[0][0];
  char* KsB = (char*)&Ks[0][0];

  for (int i = tid; i < NHEAD * 64; i += 256)
    zl[i >> 6][i & 63] =
        1.0f / (8.0f * Zsum[((long)nb * NHEAD + (i >> 6)) * L_SEQ + lb + (i & 63)]);

  auto stage = [&](int h) {
    const long qb = ((long)(nb * NHEAD + h) * L_SEQ + lb) * 128;
    const long kb = ((long)(nb * NHEAD + h) * L_SEQ + mb) * 128;
#pragma unroll
    for (int i = 0; i < 4; ++i) {
      int r = 16 * w + 4 * i + srow;
      int gc = scl ^ (r & 7);
      gl_lds16(&qph[qb + (long)r * 128 + gc * 8], &Qs[16 * w + 4 * i][0]);
      gl_lds16(&kph[kb + (long)r * 128 + gc * 8], &Ks[16 * w + 4 * i][0]);
    }
  };
  stage(0);
  __syncthreads();

  f32x4 wacc[4] = {};
  const int l0 = lb + 16 * w + 4 * g;
  for (int h = 0; h < NHEAD; ++h) {
    f16x8 qf[4];
    int qr = 16 * w + cc;
#pragma unroll
    for (int s = 0; s < 4; ++s)
      qf[s] = *(const f16x8*)(QsB + qr * 256 + ((64 * s + 16 * g) ^ ((qr & 7) << 4)));
    f32x4 zv = *(const f32x4*)&zl[h][16 * w + 4 * g];
#pragma unroll
    for (int t = 0; t < 4; ++t) {
      int kr = 16 * t + cc;
      f32x4 acc = {0.f, 0.f, 0.f, 0.f};
#pragma unroll
      for (int s = 0; s < 4; ++s) {
        f16x8 kf = *(const f16x8*)(KsB + kr * 256 + ((64 * s + 16 * g) ^ ((kr & 7) << 4)));
        acc = __builtin_amdgcn_mfma_f32_16x16x32_f16(qf[s], kf, acc, 0, 0, 0);
      }
      int m = mb + 16 * t + cc;
#pragma unroll
      for (int rg = 0; rg < 4; ++rg) {
        float e = __expf(acc[rg]) * zv[rg];
        wacc[t][rg] += (!diag || m <= l0 + rg) ? e : 0.f;
      }
    }
    if (h + 1 < NHEAD) {
      __syncthreads();
      stage(h + 1);
      __syncthreads();
    }
  }
  float* wout = wmean + (long)nb * L_SEQ * L_SEQ;
#pragma unroll
  for (int t = 0; t < 4; ++t) {
    int m = mb + 16 * t + cc;
#pragma unroll
    for (int rg = 0; rg < 4; ++rg)
      wout[(long)(l0 + rg) * L_SEQ + m] = wacc[t][rg];
  }
}

// ---------------------------------------------------------------------------
extern "C" void kernel_launch(void* const* d_in, const int* in_sizes, int n_in,
                              void* d_out, int out_size, void* d_ws, size_t ws_size,
                              hipStream_t stream)
{
  const float* q  = (const float*)d_in[0];
  const float* k  = (const float*)d_in[1];
  const float* v  = (const float*)d_in[2];
  const float* Wq = (const float*)d_in[3];
  const float* bq = (const float*)d_in[4];
  const float* Wk = (const float*)d_in[5];
  const float* bk = (const float*)d_in[6];
  const float* Wv = (const float*)d_in[7];
  const float* bv = (const float*)d_in[8];
  const float* Wo = (const float*)d_in[9];
  const float* bo = (const float*)d_in[10];

  float* out = (float*)d_out;
  float* wmean = out + (long)L_SEQ * NBATCH * DMODEL;

  if (ws_size < (106UL << 20)) return;

  char* ws = (char*)d_ws;
  _Float16* xh   = (_Float16*)(ws);                   // 48 MB (q,k,v f16)
  _Float16* qph  = (_Float16*)(ws + (48L << 20));     // 16 MB head-major
  _Float16* kph  = (_Float16*)(ws + (64L << 20));     // 16 MB head-major
  _Float16* voT  = (_Float16*)(ws + (80L << 20));     // 16 MB
  _Float16* WqT  = (_Float16*)(ws + (96L << 20));     // 2 MB
  _Float16* WkT  = (_Float16*)(ws + (98L << 20));     // 2 MB
  _Float16* WoT  = (_Float16*)(ws + (100L << 20));    // 2 MB
  _Float16* WvoT = (_Float16*)(ws + (102L << 20));    // 2 MB
  float*    bvo  = (float*)   (ws + (104L << 20));    // 4 KB
  float*    Zsum = (float*)   (ws + (104L << 20) + (1L << 16));  // 256 KB

  // zero Zsum (s1's atomic accumulator)
  zero1<<<dim3(64, 1, 1), 256, 0, stream>>>(
      (float4*)Zsum, (long)NBATCH * NHEAD * L_SEQ / 4);
  transpose3<<<dim3(32, 32, 3), dim3(32, 8, 1), 0, stream>>>(
      Wq, Wk, Wo, WqT, WkT, WoT);
  bias_proj<<<dim3(4, 1, 1), 256, 0, stream>>>(bv, Wo, bvo);
  gemm16<true, false><<<dim3(8, 8, 1), 256, 0, stream>>>(
      WoT, 1024, 0, Wv, 1024, 0,
      (float*)nullptr, 0, 0, WvoT, 1024, 0,
      (const float*)nullptr, 0, 1.0f, 1024, 0, 0);
  // f32->f16 for q,k,v in one launch
  cvt3<<<dim3(12288, 1, 1), 256, 0, stream>>>(q, k, v, xh);
  // q & k projections fused (head-major out)
  projqk<<<dim3(1024, 2, 1), 256, 0, stream>>>(xh, WqT, WkT, bq, bk, qph, kph);
  // voT[nb][d][m] = sum_c WvoT[d][c] * vh[m*4+nb][c] + bvo[d]
  proj64<<<dim3(256, 1, 4), 256, 0, stream>>>(
      WvoT, 1024, 0, xh + 2 * NQ, 4096, 1024, voT, 2048, 2048L * 1024,
      bvo, 1, 1.0f, 1024, 0, 16);
  // Softmax stats (K-split), upper zeros, head-avg weights
  s1_kernel<<<dim3(80, NHEAD, NBATCH), 256, 0, stream>>>(qph, kph, Zsum);
  zero_fill<<<dim3(120, 4, 1), 256, 0, stream>>>(wmean);
  s2_kernel<<<dim3(528, NBATCH, 1), 256, 0, stream>>>(qph, kph, Zsum, wmean);
  // out = wmean @ voT^T + bo (causal, heavy-first, direct stores)
  out_gemm<<<dim3(1024, 1, 1), 256, 0, stream>>>(wmean, voT, bo, out);
}

// Round 13
// 325.614 us; speedup vs baseline: 1.1146x; 1.0208x over previous
//
#include <hip/hip_runtime.h>

// R13: s2 emits an f16 copy of wmean (wmean16, ws) — diag-block mask zeros
// included; out_gemm16 reads it with dual gl_lds (A-fetch halved, VALU cvt
// staging gone) on the proven 64x128/1024-block heavy-first grid. Rest = R12
// (332us best).

#define L_SEQ 2048
#define NBATCH 4
#define DMODEL 1024
#define NHEAD 8
#define SCALING 0.08838834764831845f
#define NQ (2048L * 4 * 1024)

typedef _Float16 f16x8 __attribute__((ext_vector_type(8)));
typedef float f32x4 __attribute__((ext_vector_type(4)));

#define GLOBAL_AS __attribute__((address_space(1)))
#define LDS_AS __attribute__((address_space(3)))

__device__ __forceinline__ unsigned short f2h_bits(float x) {
  _Float16 h = (_Float16)x;
  return __builtin_bit_cast(unsigned short, h);
}

__device__ __forceinline__ void gl_lds16(const void* g, void* l) {
  __builtin_amdgcn_global_load_lds((GLOBAL_AS void*)g, (LDS_AS void*)l, 16, 0, 0);
}

// ---------------------------------------------------------------------------
__global__ __launch_bounds__(256) void zero1(float4* __restrict__ a, long n4)
{
  float4 z = {0.f, 0.f, 0.f, 0.f};
  long stride = (long)gridDim.x * 256;
  for (long i = (long)blockIdx.x * 256 + threadIdx.x; i < n4; i += stride)
    a[i] = z;
}

// ---------------------------------------------------------------------------
__global__ __launch_bounds__(256) void cvt3(
    const float* __restrict__ q, const float* __restrict__ k,
    const float* __restrict__ v, _Float16* __restrict__ xh)
{
  long i = ((long)blockIdx.x * 256 + threadIdx.x) * 8;
  if (i >= 3 * NQ) return;
  int which = (int)(i / NQ);
  const float* src = which == 0 ? q : (which == 1 ? k : v);
  long off = i - (long)which * NQ;
  float4 a = *(const float4*)(src + off);
  float4 b = *(const float4*)(src + off + 4);
  f16x8 h;
  h[0] = (_Float16)a.x; h[1] = (_Float16)a.y; h[2] = (_Float16)a.z; h[3] = (_Float16)a.w;
  h[4] = (_Float16)b.x; h[5] = (_Float16)b.y; h[6] = (_Float16)b.z; h[7] = (_Float16)b.w;
  *(f16x8*)(xh + i) = h;
}

// ---------------------------------------------------------------------------
// gemm16: 128x128 tile. Retained for the small Wvo prep GEMM only.
// ---------------------------------------------------------------------------
template <bool AF16, bool BF16>
__global__ __launch_bounds__(256) void gemm16(
    const void* __restrict__ Ap, long lda, long a_bs,
    const void* __restrict__ Bp, long ldb, long b_bs,
    float* __restrict__ C, long ldc, long c_bs,
    _Float16* __restrict__ Ch, long ldch, long ch_bs,
    const float* __restrict__ bias, int bias_row, float alpha, int K,
    int causal, int cmode)
{
  __shared__ __align__(16) _Float16 As[128][64];
  __shared__ __align__(16) _Float16 Bs[128][64];
  const int tid = threadIdx.x;
  const int lane = tid & 63, wv = tid >> 6;
  const int g = lane >> 4, cc = lane & 15;
  const int wm = wv >> 1, wn = wv & 1;
  const long m0 = (long)blockIdx.y * 128;
  const long n0 = (long)blockIdx.x * 128;

  const float* Af = nullptr; const _Float16* Ah = nullptr;
  const float* Bf = nullptr; const _Float16* Bh = nullptr;
  if constexpr (AF16) Ah = (const _Float16*)Ap + (long)blockIdx.z * a_bs;
  else                Af = (const float*)Ap + (long)blockIdx.z * a_bs;
  if constexpr (BF16) Bh = (const _Float16*)Bp + (long)blockIdx.z * b_bs;
  else                Bf = (const float*)Bp + (long)blockIdx.z * b_bs;

  int Keff = K;
  if (causal) { int lim = (int)m0 + 128; if (lim < K) Keff = lim; }
  const int NT = Keff >> 6;

  f32x4 acc[4][4] = {};
  char* AsB = (char*)&As[0][0];
  char* BsB = (char*)&Bs[0][0];

  for (int kt = 0; kt < NT; ++kt) {
    const long k0 = (long)kt << 6;
    __syncthreads();
    if constexpr (AF16) {
#pragma unroll
      for (int i = 0; i < 4; ++i) {
        int r = 32 * wv + 8 * i + (lane >> 3);
        int gc = (lane & 7) ^ (r & 7);
        gl_lds16(Ah + (m0 + r) * lda + k0 + gc * 8, &As[32 * wv + 8 * i][0]);
      }
    } else {
#pragma unroll
      for (int p = 0; p < 8; ++p) {
        int r = p * 16 + (tid >> 4);
        float4 vv = *(const float4*)(Af + (m0 + r) * lda + k0 + (tid & 15) * 4);
        ushort4 hh;
        hh.x = f2h_bits(vv.x); hh.y = f2h_bits(vv.y);
        hh.z = f2h_bits(vv.z); hh.w = f2h_bits(vv.w);
        *(ushort4*)(AsB + r * 128 + (((tid & 15) * 8) ^ ((r & 7) << 4))) = hh;
      }
    }
    if constexpr (BF16) {
#pragma unroll
      for (int i = 0; i < 4; ++i) {
        int r = 32 * wv + 8 * i + (lane >> 3);
        int gc = (lane & 7) ^ (r & 7);
        gl_lds16(Bh + (n0 + r) * ldb + k0 + gc * 8, &Bs[32 * wv + 8 * i][0]);
      }
    } else {
#pragma unroll
      for (int p = 0; p < 8; ++p) {
        int r = p * 16 + (tid >> 4);
        float4 vv = *(const float4*)(Bf + (n0 + r) * ldb + k0 + (tid & 15) * 4);
        ushort4 hh;
        hh.x = f2h_bits(vv.x); hh.y = f2h_bits(vv.y);
        hh.z = f2h_bits(vv.z); hh.w = f2h_bits(vv.w);
        *(ushort4*)(BsB + r * 128 + (((tid & 15) * 8) ^ ((r & 7) << 4))) = hh;
      }
    }
    __syncthreads();
#pragma unroll
    for (int s = 0; s < 2; ++s) {
      f16x8 af[4], bfr[4];
#pragma unroll
      for (int mi = 0; mi < 4; ++mi) {
        int r = wm * 64 + mi * 16 + cc;
        af[mi] = *(const f16x8*)(AsB + r * 128 + ((s * 64 + 16 * g) ^ ((r & 7) << 4)));
      }
#pragma unroll
      for (int ni = 0; ni < 4; ++ni) {
        int r = wn * 64 + ni * 16 + cc;
        bfr[ni] = *(const f16x8*)(BsB + r * 128 + ((s * 64 + 16 * g) ^ ((r & 7) << 4)));
      }
#pragma unroll
      for (int mi = 0; mi < 4; ++mi)
#pragma unroll
        for (int ni = 0; ni < 4; ++ni)
          acc[mi][ni] = __builtin_amdgcn_mfma_f32_16x16x32_f16(af[mi], bfr[ni], acc[mi][ni], 0, 0, 0);
    }
  }

  float* Cp = C ? C + (long)blockIdx.z * c_bs : nullptr;
  _Float16* Chp = Ch ? Ch + (long)blockIdx.z * ch_bs : nullptr;
#pragma unroll
  for (int ni = 0; ni < 4; ++ni) {
    long col = n0 + wn * 64 + ni * 16 + cc;
    float bcol = (bias && !bias_row) ? bias[col] : 0.0f;
#pragma unroll
    for (int mi = 0; mi < 4; ++mi) {
      long row0 = m0 + wm * 64 + mi * 16 + 4 * g;
#pragma unroll
      for (int rg = 0; rg < 4; ++rg) {
        long row = row0 + rg;
        float b = (bias && bias_row) ? bias[row] : bcol;
        float vv = (acc[mi][ni][rg] + b) * alpha;
        if (Cp) Cp[row * ldc + col] = vv;
        if (Chp) {
          if (cmode == 1) {
            long idx = (((row & 3) * NHEAD + (col >> 7)) * (long)L_SEQ + (row >> 2)) * 128 +
                       (col & 127);
            Chp[idx] = (_Float16)vv;
          } else {
            Chp[row * ldch + col] = (_Float16)vv;
          }
        }
      }
    }
  }
}

// ---------------------------------------------------------------------------
// projqk (R11, proven): q and k projections in one launch.
// ---------------------------------------------------------------------------
__global__ __launch_bounds__(256) void projqk(
    const _Float16* __restrict__ xh, const _Float16* __restrict__ WqT,
    const _Float16* __restrict__ WkT, const float* __restrict__ bq,
    const float* __restrict__ bk, _Float16* __restrict__ qph,
    _Float16* __restrict__ kph)
{
  __shared__ __align__(16) _Float16 As[64][64];
  __shared__ __align__(16) _Float16 Bs[128][64];
  const int tid = threadIdx.x, lane = tid & 63, wv = tid >> 6;
  const int g = lane >> 4, cc = lane & 15;
  const int wm = wv >> 1, wn = wv & 1;
  const int sel = (int)blockIdx.y;
  const _Float16* A = xh + (long)sel * NQ;
  const _Float16* B = sel ? WkT : WqT;
  const float* bias = sel ? bk : bq;
  const float alpha = sel ? 1.0f : SCALING;
  _Float16* dst = sel ? kph : qph;
  const int fi = (int)blockIdx.x;
  const long m0 = (long)(fi >> 3) * 64;
  const long n0 = (long)(fi & 7) * 128;

  f32x4 acc[2][4] = {};
  char* AsB = (char*)&As[0][0];
  char* BsB = (char*)&Bs[0][0];

  for (int kt = 0; kt < 16; ++kt) {
    const long k0 = (long)kt << 6;
    __syncthreads();
#pragma unroll
    for (int i = 0; i < 2; ++i) {
      int r = 16 * wv + 8 * i + (lane >> 3);
      int gc = (lane & 7) ^ (r & 7);
      gl_lds16(A + (m0 + r) * 1024 + k0 + gc * 8, &As[16 * wv + 8 * i][0]);
    }
#pragma unroll
    for (int i = 0; i < 4; ++i) {
      int r = 32 * wv + 8 * i + (lane >> 3);
      int gc = (lane & 7) ^ (r & 7);
      gl_lds16(B + (n0 + r) * 1024 + k0 + gc * 8, &Bs[32 * wv + 8 * i][0]);
    }
    __syncthreads();
#pragma unroll
    for (int s = 0; s < 2; ++s) {
      f16x8 af[2], bfr[4];
#pragma unroll
      for (int mi = 0; mi < 2; ++mi) {
        int r = wm * 32 + mi * 16 + cc;
        af[mi] = *(const f16x8*)(AsB + r * 128 + ((s * 64 + 16 * g) ^ ((r & 7) << 4)));
      }
#pragma unroll
      for (int ni = 0; ni < 4; ++ni) {
        int r = wn * 64 + ni * 16 + cc;
        bfr[ni] = *(const f16x8*)(BsB + r * 128 + ((s * 64 + 16 * g) ^ ((r & 7) << 4)));
      }
#pragma unroll
      for (int mi = 0; mi < 2; ++mi)
#pragma unroll
        for (int ni = 0; ni < 4; ++ni)
          acc[mi][ni] = __builtin_amdgcn_mfma_f32_16x16x32_f16(af[mi], bfr[ni], acc[mi][ni], 0, 0, 0);
    }
  }

#pragma unroll
  for (int ni = 0; ni < 4; ++ni) {
    long col = n0 + wn * 64 + ni * 16 + cc;
    float bcol = bias[col];
#pragma unroll
    for (int mi = 0; mi < 2; ++mi) {
      long row0 = m0 + wm * 32 + mi * 16 + 4 * g;
#pragma unroll
      for (int rg = 0; rg < 4; ++rg) {
        long row = row0 + rg;
        float vv = (acc[mi][ni][rg] + bcol) * alpha;
        long idx = (((row & 3) * NHEAD + (col >> 7)) * (long)L_SEQ + (row >> 2)) * 128 +
                   (col & 127);
        dst[idx] = (_Float16)vv;
      }
    }
  }
}

// ---------------------------------------------------------------------------
// proj64 (R8, proven): 64x128 tile, all-f16 dual gl_lds staging. For voT.
// ---------------------------------------------------------------------------
__global__ __launch_bounds__(256) void proj64(
    const _Float16* __restrict__ Ap, long lda, long a_bs,
    const _Float16* __restrict__ Bp, long ldb, long b_bs,
    _Float16* __restrict__ Ch, long ldch, long ch_bs,
    const float* __restrict__ bias, int bias_row, float alpha, int K,
    int cmode, int ntiles)
{
  __shared__ __align__(16) _Float16 As[64][64];
  __shared__ __align__(16) _Float16 Bs[128][64];
  const int tid = threadIdx.x, lane = tid & 63, wv = tid >> 6;
  const int g = lane >> 4, cc = lane & 15;
  const int wm = wv >> 1, wn = wv & 1;
  const int fi = (int)blockIdx.x;
  const int by = fi / ntiles, nc = fi % ntiles;
  const long m0 = (long)by * 64;
  const long n0 = (long)nc * 128;
  const _Float16* A = Ap + (long)blockIdx.z * a_bs;
  const _Float16* B = Bp + (long)blockIdx.z * b_bs;
  const int NT = K >> 6;

  f32x4 acc[2][4] = {};
  char* AsB = (char*)&As[0][0];
  char* BsB = (char*)&Bs[0][0];

  for (int kt = 0; kt < NT; ++kt) {
    const long k0 = (long)kt << 6;
    __syncthreads();
#pragma unroll
    for (int i = 0; i < 2; ++i) {
      int r = 16 * wv + 8 * i + (lane >> 3);
      int gc = (lane & 7) ^ (r & 7);
      gl_lds16(A + (m0 + r) * lda + k0 + gc * 8, &As[16 * wv + 8 * i][0]);
    }
#pragma unroll
    for (int i = 0; i < 4; ++i) {
      int r = 32 * wv + 8 * i + (lane >> 3);
      int gc = (lane & 7) ^ (r & 7);
      gl_lds16(B + (n0 + r) * ldb + k0 + gc * 8, &Bs[32 * wv + 8 * i][0]);
    }
    __syncthreads();
#pragma unroll
    for (int s = 0; s < 2; ++s) {
      f16x8 af[2], bfr[4];
#pragma unroll
      for (int mi = 0; mi < 2; ++mi) {
        int r = wm * 32 + mi * 16 + cc;
        af[mi] = *(const f16x8*)(AsB + r * 128 + ((s * 64 + 16 * g) ^ ((r & 7) << 4)));
      }
#pragma unroll
      for (int ni = 0; ni < 4; ++ni) {
        int r = wn * 64 + ni * 16 + cc;
        bfr[ni] = *(const f16x8*)(BsB + r * 128 + ((s * 64 + 16 * g) ^ ((r & 7) << 4)));
      }
#pragma unroll
      for (int mi = 0; mi < 2; ++mi)
#pragma unroll
        for (int ni = 0; ni < 4; ++ni)
          acc[mi][ni] = __builtin_amdgcn_mfma_f32_16x16x32_f16(af[mi], bfr[ni], acc[mi][ni], 0, 0, 0);
    }
  }

  _Float16* Chp = Ch + (long)blockIdx.z * ch_bs;
#pragma unroll
  for (int ni = 0; ni < 4; ++ni) {
    long col = n0 + wn * 64 + ni * 16 + cc;
    float bcol = bias_row ? 0.0f : bias[col];
#pragma unroll
    for (int mi = 0; mi < 2; ++mi) {
      long row0 = m0 + wm * 32 + mi * 16 + 4 * g;
#pragma unroll
      for (int rg = 0; rg < 4; ++rg) {
        long row = row0 + rg;
        float b = bias_row ? bias[row] : bcol;
        float vv = (acc[mi][ni][rg] + b) * alpha;
        if (cmode == 1) {
          long idx = (((row & 3) * NHEAD + (col >> 7)) * (long)L_SEQ + (row >> 2)) * 128 +
                     (col & 127);
          Chp[idx] = (_Float16)vv;
        } else {
          Chp[row * ldch + col] = (_Float16)vv;
        }
      }
    }
  }
}

// ---------------------------------------------------------------------------
// out_gemm16: out = wmean16 @ voT^T + bo, causal. Both operands f16 via
// gl_lds (A-fetch halved vs f32 wmean, no VALU cvt staging). 64x128 tiles,
// 1024 blocks heavy-first, 24KB LDS, direct stores.
// ---------------------------------------------------------------------------
__global__ __launch_bounds__(256) void out_gemm16(
    const _Float16* __restrict__ wm16, const _Float16* __restrict__ voT,
    const float* __restrict__ bo, float* __restrict__ out)
{
  __shared__ __align__(16) _Float16 As[64][64];
  __shared__ __align__(16) _Float16 Bs[128][64];
  const int tid = threadIdx.x, lane = tid & 63, wv = tid >> 6;
  const int g = lane >> 4, cc = lane & 15;
  const int wm = wv >> 1, wn = wv & 1;
  const int fi = (int)blockIdx.x;
  const int by = 31 - (fi >> 5);            // heavy (long-K) blocks first
  const int j = fi & 31;
  const int nb = j >> 3, nc = j & 7;
  const long m0 = (long)by * 64;
  const long n0 = (long)nc * 128;
  const _Float16* A = wm16 + (long)nb * L_SEQ * L_SEQ;
  const _Float16* B = voT + (long)nb * 2048L * 1024;
  const int NT = by + 1;

  f32x4 acc[2][4] = {};
  char* AsB = (char*)&As[0][0];
  char* BsB = (char*)&Bs[0][0];

  for (int kt = 0; kt < NT; ++kt) {
    const long k0 = (long)kt << 6;
    __syncthreads();
#pragma unroll
    for (int i = 0; i < 2; ++i) {
      int r = 16 * wv + 8 * i + (lane >> 3);
      int gc = (lane & 7) ^ (r & 7);
      gl_lds16(A + (m0 + r) * 2048 + k0 + gc * 8, &As[16 * wv + 8 * i][0]);
    }
#pragma unroll
    for (int i = 0; i < 4; ++i) {
      int r = 32 * wv + 8 * i + (lane >> 3);
      int gc = (lane & 7) ^ (r & 7);
      gl_lds16(B + (n0 + r) * 2048 + k0 + gc * 8, &Bs[32 * wv + 8 * i][0]);
    }
    __syncthreads();
#pragma unroll
    for (int s = 0; s < 2; ++s) {
      f16x8 af[2], bfr[4];
#pragma unroll
      for (int mi = 0; mi < 2; ++mi) {
        int r = wm * 32 + mi * 16 + cc;
        af[mi] = *(const f16x8*)(AsB + r * 128 + ((s * 64 + 16 * g) ^ ((r & 7) << 4)));
      }
#pragma unroll
      for (int ni = 0; ni < 4; ++ni) {
        int r = wn * 64 + ni * 16 + cc;
        bfr[ni] = *(const f16x8*)(BsB + r * 128 + ((s * 64 + 16 * g) ^ ((r & 7) << 4)));
      }
#pragma unroll
      for (int mi = 0; mi < 2; ++mi)
#pragma unroll
        for (int ni = 0; ni < 4; ++ni)
          acc[mi][ni] = __builtin_amdgcn_mfma_f32_16x16x32_f16(af[mi], bfr[ni], acc[mi][ni], 0, 0, 0);
    }
  }

#pragma unroll
  for (int ni = 0; ni < 4; ++ni) {
    long col = n0 + wn * 64 + ni * 16 + cc;
    float b = bo[col];
#pragma unroll
    for (int mi = 0; mi < 2; ++mi) {
      long l0 = m0 + wm * 32 + mi * 16 + 4 * g;
#pragma unroll
      for (int rg = 0; rg < 4; ++rg)
        out[(l0 + rg) * 4096 + nb * 1024 + col] = acc[mi][ni][rg] + b;
    }
  }
}

// ---------------------------------------------------------------------------
__global__ __launch_bounds__(256) void transpose3(
    const float* __restrict__ s0, const float* __restrict__ s1,
    const float* __restrict__ s2,
    _Float16* __restrict__ d0, _Float16* __restrict__ d1,
    _Float16* __restrict__ d2)
{
  __shared__ _Float16 tile[32][33];
  const float* in = blockIdx.z == 0 ? s0 : (blockIdx.z == 1 ? s1 : s2);
  _Float16* outp = blockIdx.z == 0 ? d0 : (blockIdx.z == 1 ? d1 : d2);
  int r0 = blockIdx.y * 32, c0 = blockIdx.x * 32;
  for (int i = threadIdx.y; i < 32; i += 8)
    tile[i][threadIdx.x] = (_Float16)in[(long)(r0 + i) * 1024 + c0 + threadIdx.x];
  __syncthreads();
  for (int i = threadIdx.y; i < 32; i += 8)
    outp[(long)(c0 + i) * 1024 + r0 + threadIdx.x] = tile[threadIdx.x][i];
}

__global__ __launch_bounds__(256) void bias_proj(
    const float* __restrict__ bv, const float* __restrict__ Wo, float* __restrict__ bvo)
{
  int j = blockIdx.x * 256 + threadIdx.x;
  float acc = 0.f;
  for (int i = 0; i < DMODEL; ++i) acc += bv[i] * Wo[(long)i * DMODEL + j];
  bvo[j] = acc;
}

// ---------------------------------------------------------------------------
// S1 (R10, proven): K-split partial Zsum via atomicAdd. 80-segment grid.
// ---------------------------------------------------------------------------
__global__ __launch_bounds__(256) void s1_kernel(
    const _Float16* __restrict__ qph, const _Float16* __restrict__ kph,
    float* __restrict__ Zsum)
{
  __shared__ __align__(16) _Float16 Qs[64][128];
  __shared__ __align__(16) _Float16 Ks[64][128];
  const int tid = threadIdx.x, lane = tid & 63, w = tid >> 6;
  const int g = lane >> 4, cc = lane & 15;
  const int h = blockIdx.y, nb = blockIdx.z;
  int fi = 79 - (int)blockIdx.x;
  int by, seg;
  if (fi < 8)       { by = fi;                  seg = 0; }
  else if (fi < 24) { int t = fi - 8;  by = 8  + (t >> 1); seg = t & 1; }
  else if (fi < 48) { int t = fi - 24; by = 16 + t / 3;    seg = t % 3; }
  else              { int t = fi - 48; by = 24 + (t >> 2); seg = t & 3; }
  const int lb = by * 64;
  const int c0 = seg * 8;
  const int cEnd = min(c0 + 8, by + 1);
  const int srow = lane >> 4, scl = lane & 15;
  const long hb = ((long)(nb * NHEAD + h)) * L_SEQ * 128;
  char* QsB = (char*)&Qs[0][0];
  char* KsB = (char*)&Ks[0][0];

#pragma unroll
  for (int i = 0; i < 4; ++i) {
    int r = 16 * w + 4 * i + srow;
    int gc = scl ^ (r & 7);
    gl_lds16(&qph[hb + (long)(lb + r) * 128 + gc * 8], &Qs[16 * w + 4 * i][0]);
  }
  auto stageK = [&](int ch) {
#pragma unroll
    for (int i = 0; i < 4; ++i) {
      int r = 16 * w + 4 * i + srow;
      int gc = scl ^ (r & 7);
      gl_lds16(&kph[hb + (long)(ch * 64 + r) * 128 + gc * 8], &Ks[16 * w + 4 * i][0]);
    }
  };
  stageK(c0);
  __syncthreads();

  f16x8 qf[4];
  {
    int r = 16 * w + cc;
#pragma unroll
    for (int s = 0; s < 4; ++s)
      qf[s] = *(const f16x8*)(QsB + r * 256 + ((64 * s + 16 * g) ^ ((r & 7) << 4)));
  }

  f32x4 zacc = {0.f, 0.f, 0.f, 0.f};
  const int l0 = lb + 16 * w + 4 * g;
  for (int ch = c0; ch < cEnd; ++ch) {
#pragma unroll
    for (int t = 0; t < 4; ++t) {
      int kr = 16 * t + cc;
      f32x4 acc = {0.f, 0.f, 0.f, 0.f};
#pragma unroll
      for (int s = 0; s < 4; ++s) {
        f16x8 kf = *(const f16x8*)(KsB + kr * 256 + ((64 * s + 16 * g) ^ ((kr & 7) << 4)));
        acc = __builtin_amdgcn_mfma_f32_16x16x32_f16(qf[s], kf, acc, 0, 0, 0);
      }
      int m = ch * 64 + 16 * t + cc;
#pragma unroll
      for (int rg = 0; rg < 4; ++rg) {
        float e = __expf(acc[rg]);
        zacc[rg] += (m <= l0 + rg) ? e : 0.f;
      }
    }
    if (ch + 1 < cEnd) {
      __syncthreads();
      stageK(ch + 1);
      __syncthreads();
    }
  }
#pragma unroll
  for (int rg = 0; rg < 4; ++rg) {
    float vv = zacc[rg];
    vv += __shfl_xor(vv, 1, 16);
    vv += __shfl_xor(vv, 2, 16);
    vv += __shfl_xor(vv, 4, 16);
    vv += __shfl_xor(vv, 8, 16);
    if (cc == 0)
      atomicAdd(&Zsum[((long)nb * NHEAD + h) * L_SEQ + l0 + rg], vv);
  }
}

// ---------------------------------------------------------------------------
__global__ __launch_bounds__(256) void zero_fill(float* __restrict__ wmean)
{
  int t = (int)blockIdx.x, nb = (int)blockIdx.y;
  int by = 0, rem = t;
  while (rem >= 15 - by) { rem -= 15 - by; ++by; }
  const int mc = by + 1 + rem;
  const int tr = threadIdx.x >> 1, th = threadIdx.x & 1;
  float4 z4 = {0.f, 0.f, 0.f, 0.f};
  float* p = wmean + (long)nb * L_SEQ * L_SEQ + (long)(by * 128 + tr) * L_SEQ +
             mc * 128 + th * 64;
#pragma unroll
  for (int j = 0; j < 16; ++j) ((float4*)p)[j] = z4;
}

// ---------------------------------------------------------------------------
// S2 (R10 + f16 copy): 64x64 triangle tiles; writes f32 wmean (d_out) AND
// f16 wmean16 (ws, feeds out_gemm16 — diag-mask zeros included).
// ---------------------------------------------------------------------------
__global__ __launch_bounds__(256) void s2_kernel(
    const _Float16* __restrict__ qph, const _Float16* __restrict__ kph,
    const float* __restrict__ Zsum, float* __restrict__ wmean,
    _Float16* __restrict__ wm16)
{
  __shared__ __align__(16) _Float16 Qs[64][128];
  __shared__ __align__(16) _Float16 Ks[64][128];
  __shared__ float zl[NHEAD][64];
  const int tid = threadIdx.x, lane = tid & 63, w = tid >> 6;
  const int g = lane >> 4, cc = lane & 15;
  const int nb = blockIdx.y;
  int b = (int)blockIdx.x;
  int bx = (b & 7) * 66 + (b >> 3);          // XCD swizzle (528 = 8*66)
  int by = 0, rem = bx;
  while (rem > by) { rem -= by + 1; ++by; }
  const int mc = rem;
  const int lb = by * 64, mb = mc * 64;
  const bool diag = (mc == by);
  const int srow = lane >> 4, scl = lane & 15;
  char* QsB = (char*)&Qs[0][0];
  char* KsB = (char*)&Ks[0][0];

  for (int i = tid; i < NHEAD * 64; i += 256)
    zl[i >> 6][i & 63] =
        1.0f / (8.0f * Zsum[((long)nb * NHEAD + (i >> 6)) * L_SEQ + lb + (i & 63)]);

  auto stage = [&](int h) {
    const long qb = ((long)(nb * NHEAD + h) * L_SEQ + lb) * 128;
    const long kb = ((long)(nb * NHEAD + h) * L_SEQ + mb) * 128;
#pragma unroll
    for (int i = 0; i < 4; ++i) {
      int r = 16 * w + 4 * i + srow;
      int gc = scl ^ (r & 7);
      gl_lds16(&qph[qb + (long)r * 128 + gc * 8], &Qs[16 * w + 4 * i][0]);
      gl_lds16(&kph[kb + (long)r * 128 + gc * 8], &Ks[16 * w + 4 * i][0]);
    }
  };
  stage(0);
  __syncthreads();

  f32x4 wacc[4] = {};
  const int l0 = lb + 16 * w + 4 * g;
  for (int h = 0; h < NHEAD; ++h) {
    f16x8 qf[4];
    int qr = 16 * w + cc;
#pragma unroll
    for (int s = 0; s < 4; ++s)
      qf[s] = *(const f16x8*)(QsB + qr * 256 + ((64 * s + 16 * g) ^ ((qr & 7) << 4)));
    f32x4 zv = *(const f32x4*)&zl[h][16 * w + 4 * g];
#pragma unroll
    for (int t = 0; t < 4; ++t) {
      int kr = 16 * t + cc;
      f32x4 acc = {0.f, 0.f, 0.f, 0.f};
#pragma unroll
      for (int s = 0; s < 4; ++s) {
        f16x8 kf = *(const f16x8*)(KsB + kr * 256 + ((64 * s + 16 * g) ^ ((kr & 7) << 4)));
        acc = __builtin_amdgcn_mfma_f32_16x16x32_f16(qf[s], kf, acc, 0, 0, 0);
      }
      int m = mb + 16 * t + cc;
#pragma unroll
      for (int rg = 0; rg < 4; ++rg) {
        float e = __expf(acc[rg]) * zv[rg];
        wacc[t][rg] += (!diag || m <= l0 + rg) ? e : 0.f;
      }
    }
    if (h + 1 < NHEAD) {
      __syncthreads();
      stage(h + 1);
      __syncthreads();
    }
  }
  float* wout = wmean + (long)nb * L_SEQ * L_SEQ;
  _Float16* w16 = wm16 + (long)nb * L_SEQ * L_SEQ;
#pragma unroll
  for (int t = 0; t < 4; ++t) {
    int m = mb + 16 * t + cc;
#pragma unroll
    for (int rg = 0; rg < 4; ++rg) {
      long idx = (long)(l0 + rg) * L_SEQ + m;
      wout[idx] = wacc[t][rg];
      w16[idx] = (_Float16)wacc[t][rg];
    }
  }
}

// ---------------------------------------------------------------------------
extern "C" void kernel_launch(void* const* d_in, const int* in_sizes, int n_in,
                              void* d_out, int out_size, void* d_ws, size_t ws_size,
                              hipStream_t stream)
{
  const float* q  = (const float*)d_in[0];
  const float* k  = (const float*)d_in[1];
  const float* v  = (const float*)d_in[2];
  const float* Wq = (const float*)d_in[3];
  const float* bq = (const float*)d_in[4];
  const float* Wk = (const float*)d_in[5];
  const float* bk = (const float*)d_in[6];
  const float* Wv = (const float*)d_in[7];
  const float* bv = (const float*)d_in[8];
  const float* Wo = (const float*)d_in[9];
  const float* bo = (const float*)d_in[10];

  float* out = (float*)d_out;
  float* wmean = out + (long)L_SEQ * NBATCH * DMODEL;

  if (ws_size < (140UL << 20)) return;

  char* ws = (char*)d_ws;
  _Float16* xh   = (_Float16*)(ws);                   // 48 MB (q,k,v f16)
  _Float16* qph  = (_Float16*)(ws + (48L << 20));     // 16 MB head-major
  _Float16* kph  = (_Float16*)(ws + (64L << 20));     // 16 MB head-major
  _Float16* voT  = (_Float16*)(ws + (80L << 20));     // 16 MB
  _Float16* wm16 = (_Float16*)(ws + (96L << 20));     // 33.6 MB (f16 wmean)
  _Float16* WqT  = (_Float16*)(ws + (130L << 20));    // 2 MB
  _Float16* WkT  = (_Float16*)(ws + (132L << 20));    // 2 MB
  _Float16* WoT  = (_Float16*)(ws + (134L << 20));    // 2 MB
  _Float16* WvoT = (_Float16*)(ws + (136L << 20));    // 2 MB
  float*    bvo  = (float*)   (ws + (138L << 20));    // 4 KB
  float*    Zsum = (float*)   (ws + (138L << 20) + (1L << 16));  // 256 KB

  // zero Zsum (s1's atomic accumulator)
  zero1<<<dim3(64, 1, 1), 256, 0, stream>>>(
      (float4*)Zsum, (long)NBATCH * NHEAD * L_SEQ / 4);
  transpose3<<<dim3(32, 32, 3), dim3(32, 8, 1), 0, stream>>>(
      Wq, Wk, Wo, WqT, WkT, WoT);
  bias_proj<<<dim3(4, 1, 1), 256, 0, stream>>>(bv, Wo, bvo);
  gemm16<true, false><<<dim3(8, 8, 1), 256, 0, stream>>>(
      WoT, 1024, 0, Wv, 1024, 0,
      (float*)nullptr, 0, 0, WvoT, 1024, 0,
      (const float*)nullptr, 0, 1.0f, 1024, 0, 0);
  // f32->f16 for q,k,v in one launch
  cvt3<<<dim3(12288, 1, 1), 256, 0, stream>>>(q, k, v, xh);
  // q & k projections fused (head-major out)
  projqk<<<dim3(1024, 2, 1), 256, 0, stream>>>(xh, WqT, WkT, bq, bk, qph, kph);
  // voT[nb][d][m] = sum_c WvoT[d][c] * vh[m*4+nb][c] + bvo[d]
  proj64<<<dim3(256, 1, 4), 256, 0, stream>>>(
      WvoT, 1024, 0, xh + 2 * NQ, 4096, 1024, voT, 2048, 2048L * 1024,
      bvo, 1, 1.0f, 1024, 0, 16);
  // Softmax stats (K-split), upper zeros, head-avg weights (+f16 copy)
  s1_kernel<<<dim3(80, NHEAD, NBATCH), 256, 0, stream>>>(qph, kph, Zsum);
  zero_fill<<<dim3(120, 4, 1), 256, 0, stream>>>(wmean);
  s2_kernel<<<dim3(528, NBATCH, 1), 256, 0, stream>>>(qph, kph, Zsum, wmean, wm16);
  // out = wmean16 @ voT^T + bo (causal, heavy-first, dual gl_lds, f16 A)
  out_gemm16<<<dim3(1024, 1, 1), 256, 0, stream>>>(wm16, voT, bo, out);
}

// Round 14
// 314.512 us; speedup vs baseline: 1.1539x; 1.0353x over previous
//
#include <hip/hip_runtime.h>

// R14: s2 retiled to 64lx128m (272 tiles/batch, heavy-first, 50KB LDS,
// 3 blocks/CU — 2x MFMA per barrier, 6B/elem staging); prep kernel merges
// transpose3+bias_proj+Zsum-zero (11->9 launches). Rest = R13 (325.6us best).

#define L_SEQ 2048
#define NBATCH 4
#define DMODEL 1024
#define NHEAD 8
#define SCALING 0.08838834764831845f
#define NQ (2048L * 4 * 1024)

typedef _Float16 f16x8 __attribute__((ext_vector_type(8)));
typedef float f32x4 __attribute__((ext_vector_type(4)));

#define GLOBAL_AS __attribute__((address_space(1)))
#define LDS_AS __attribute__((address_space(3)))

__device__ __forceinline__ unsigned short f2h_bits(float x) {
  _Float16 h = (_Float16)x;
  return __builtin_bit_cast(unsigned short, h);
}

__device__ __forceinline__ void gl_lds16(const void* g, void* l) {
  __builtin_amdgcn_global_load_lds((GLOBAL_AS void*)g, (LDS_AS void*)l, 16, 0, 0);
}

// ---------------------------------------------------------------------------
// prep: z<3 -> weight transpose (Wq,Wk,Wo -> f16 T); z==3 -> bias_proj (y==0,
// x<4) and Zsum zeroing (y==1,2).
// ---------------------------------------------------------------------------
__global__ __launch_bounds__(256) void prep(
    const float* __restrict__ Wq, const float* __restrict__ Wk,
    const float* __restrict__ Wo,
    _Float16* __restrict__ WqT, _Float16* __restrict__ WkT,
    _Float16* __restrict__ WoT,
    const float* __restrict__ bv, float* __restrict__ bvo,
    float4* __restrict__ Zsum4)
{
  const int z = (int)blockIdx.z;
  const int tid = threadIdx.y * 32 + threadIdx.x;
  if (z == 3) {
    if (blockIdx.y == 0 && blockIdx.x < 4) {
      int j = blockIdx.x * 256 + tid;
      float acc = 0.f;
      for (int i = 0; i < DMODEL; ++i) acc += bv[i] * Wo[(long)i * DMODEL + j];
      bvo[j] = acc;
    } else if (blockIdx.y == 1 || blockIdx.y == 2) {
      long idx = ((long)(blockIdx.y - 1) * 32 + blockIdx.x) * 256 + tid;
      if (idx < (long)NBATCH * NHEAD * L_SEQ / 4)
        Zsum4[idx] = (float4){0.f, 0.f, 0.f, 0.f};
    }
    return;
  }
  __shared__ _Float16 tile[32][33];
  const float* in = z == 0 ? Wq : (z == 1 ? Wk : Wo);
  _Float16* outp = z == 0 ? WqT : (z == 1 ? WkT : WoT);
  int r0 = blockIdx.y * 32, c0 = blockIdx.x * 32;
  for (int i = threadIdx.y; i < 32; i += 8)
    tile[i][threadIdx.x] = (_Float16)in[(long)(r0 + i) * 1024 + c0 + threadIdx.x];
  __syncthreads();
  for (int i = threadIdx.y; i < 32; i += 8)
    outp[(long)(c0 + i) * 1024 + r0 + threadIdx.x] = tile[threadIdx.x][i];
}

// ---------------------------------------------------------------------------
__global__ __launch_bounds__(256) void cvt3(
    const float* __restrict__ q, const float* __restrict__ k,
    const float* __restrict__ v, _Float16* __restrict__ xh)
{
  long i = ((long)blockIdx.x * 256 + threadIdx.x) * 8;
  if (i >= 3 * NQ) return;
  int which = (int)(i / NQ);
  const float* src = which == 0 ? q : (which == 1 ? k : v);
  long off = i - (long)which * NQ;
  float4 a = *(const float4*)(src + off);
  float4 b = *(const float4*)(src + off + 4);
  f16x8 h;
  h[0] = (_Float16)a.x; h[1] = (_Float16)a.y; h[2] = (_Float16)a.z; h[3] = (_Float16)a.w;
  h[4] = (_Float16)b.x; h[5] = (_Float16)b.y; h[6] = (_Float16)b.z; h[7] = (_Float16)b.w;
  *(f16x8*)(xh + i) = h;
}

// ---------------------------------------------------------------------------
// gemm16: 128x128 tile. Retained for the small Wvo prep GEMM only.
// ---------------------------------------------------------------------------
template <bool AF16, bool BF16>
__global__ __launch_bounds__(256) void gemm16(
    const void* __restrict__ Ap, long lda, long a_bs,
    const void* __restrict__ Bp, long ldb, long b_bs,
    float* __restrict__ C, long ldc, long c_bs,
    _Float16* __restrict__ Ch, long ldch, long ch_bs,
    const float* __restrict__ bias, int bias_row, float alpha, int K,
    int causal, int cmode)
{
  __shared__ __align__(16) _Float16 As[128][64];
  __shared__ __align__(16) _Float16 Bs[128][64];
  const int tid = threadIdx.x;
  const int lane = tid & 63, wv = tid >> 6;
  const int g = lane >> 4, cc = lane & 15;
  const int wm = wv >> 1, wn = wv & 1;
  const long m0 = (long)blockIdx.y * 128;
  const long n0 = (long)blockIdx.x * 128;

  const float* Af = nullptr; const _Float16* Ah = nullptr;
  const float* Bf = nullptr; const _Float16* Bh = nullptr;
  if constexpr (AF16) Ah = (const _Float16*)Ap + (long)blockIdx.z * a_bs;
  else                Af = (const float*)Ap + (long)blockIdx.z * a_bs;
  if constexpr (BF16) Bh = (const _Float16*)Bp + (long)blockIdx.z * b_bs;
  else                Bf = (const float*)Bp + (long)blockIdx.z * b_bs;

  int Keff = K;
  if (causal) { int lim = (int)m0 + 128; if (lim < K) Keff = lim; }
  const int NT = Keff >> 6;

  f32x4 acc[4][4] = {};
  char* AsB = (char*)&As[0][0];
  char* BsB = (char*)&Bs[0][0];

  for (int kt = 0; kt < NT; ++kt) {
    const long k0 = (long)kt << 6;
    __syncthreads();
    if constexpr (AF16) {
#pragma unroll
      for (int i = 0; i < 4; ++i) {
        int r = 32 * wv + 8 * i + (lane >> 3);
        int gc = (lane & 7) ^ (r & 7);
        gl_lds16(Ah + (m0 + r) * lda + k0 + gc * 8, &As[32 * wv + 8 * i][0]);
      }
    } else {
#pragma unroll
      for (int p = 0; p < 8; ++p) {
        int r = p * 16 + (tid >> 4);
        float4 vv = *(const float4*)(Af + (m0 + r) * lda + k0 + (tid & 15) * 4);
        ushort4 hh;
        hh.x = f2h_bits(vv.x); hh.y = f2h_bits(vv.y);
        hh.z = f2h_bits(vv.z); hh.w = f2h_bits(vv.w);
        *(ushort4*)(AsB + r * 128 + (((tid & 15) * 8) ^ ((r & 7) << 4))) = hh;
      }
    }
    if constexpr (BF16) {
#pragma unroll
      for (int i = 0; i < 4; ++i) {
        int r = 32 * wv + 8 * i + (lane >> 3);
        int gc = (lane & 7) ^ (r & 7);
        gl_lds16(Bh + (n0 + r) * ldb + k0 + gc * 8, &Bs[32 * wv + 8 * i][0]);
      }
    } else {
#pragma unroll
      for (int p = 0; p < 8; ++p) {
        int r = p * 16 + (tid >> 4);
        float4 vv = *(const float4*)(Bf + (n0 + r) * ldb + k0 + (tid & 15) * 4);
        ushort4 hh;
        hh.x = f2h_bits(vv.x); hh.y = f2h_bits(vv.y);
        hh.z = f2h_bits(vv.z); hh.w = f2h_bits(vv.w);
        *(ushort4*)(BsB + r * 128 + (((tid & 15) * 8) ^ ((r & 7) << 4))) = hh;
      }
    }
    __syncthreads();
#pragma unroll
    for (int s = 0; s < 2; ++s) {
      f16x8 af[4], bfr[4];
#pragma unroll
      for (int mi = 0; mi < 4; ++mi) {
        int r = wm * 64 + mi * 16 + cc;
        af[mi] = *(const f16x8*)(AsB + r * 128 + ((s * 64 + 16 * g) ^ ((r & 7) << 4)));
      }
#pragma unroll
      for (int ni = 0; ni < 4; ++ni) {
        int r = wn * 64 + ni * 16 + cc;
        bfr[ni] = *(const f16x8*)(BsB + r * 128 + ((s * 64 + 16 * g) ^ ((r & 7) << 4)));
      }
#pragma unroll
      for (int mi = 0; mi < 4; ++mi)
#pragma unroll
        for (int ni = 0; ni < 4; ++ni)
          acc[mi][ni] = __builtin_amdgcn_mfma_f32_16x16x32_f16(af[mi], bfr[ni], acc[mi][ni], 0, 0, 0);
    }
  }

  float* Cp = C ? C + (long)blockIdx.z * c_bs : nullptr;
  _Float16* Chp = Ch ? Ch + (long)blockIdx.z * ch_bs : nullptr;
#pragma unroll
  for (int ni = 0; ni < 4; ++ni) {
    long col = n0 + wn * 64 + ni * 16 + cc;
    float bcol = (bias && !bias_row) ? bias[col] : 0.0f;
#pragma unroll
    for (int mi = 0; mi < 4; ++mi) {
      long row0 = m0 + wm * 64 + mi * 16 + 4 * g;
#pragma unroll
      for (int rg = 0; rg < 4; ++rg) {
        long row = row0 + rg;
        float b = (bias && bias_row) ? bias[row] : bcol;
        float vv = (acc[mi][ni][rg] + b) * alpha;
        if (Cp) Cp[row * ldc + col] = vv;
        if (Chp) {
          if (cmode == 1) {
            long idx = (((row & 3) * NHEAD + (col >> 7)) * (long)L_SEQ + (row >> 2)) * 128 +
                       (col & 127);
            Chp[idx] = (_Float16)vv;
          } else {
            Chp[row * ldch + col] = (_Float16)vv;
          }
        }
      }
    }
  }
}

// ---------------------------------------------------------------------------
// projqk (R11, proven): q and k projections in one launch.
// ---------------------------------------------------------------------------
__global__ __launch_bounds__(256) void projqk(
    const _Float16* __restrict__ xh, const _Float16* __restrict__ WqT,
    const _Float16* __restrict__ WkT, const float* __restrict__ bq,
    const float* __restrict__ bk, _Float16* __restrict__ qph,
    _Float16* __restrict__ kph)
{
  __shared__ __align__(16) _Float16 As[64][64];
  __shared__ __align__(16) _Float16 Bs[128][64];
  const int tid = threadIdx.x, lane = tid & 63, wv = tid >> 6;
  const int g = lane >> 4, cc = lane & 15;
  const int wm = wv >> 1, wn = wv & 1;
  const int sel = (int)blockIdx.y;
  const _Float16* A = xh + (long)sel * NQ;
  const _Float16* B = sel ? WkT : WqT;
  const float* bias = sel ? bk : bq;
  const float alpha = sel ? 1.0f : SCALING;
  _Float16* dst = sel ? kph : qph;
  const int fi = (int)blockIdx.x;
  const long m0 = (long)(fi >> 3) * 64;
  const long n0 = (long)(fi & 7) * 128;

  f32x4 acc[2][4] = {};
  char* AsB = (char*)&As[0][0];
  char* BsB = (char*)&Bs[0][0];

  for (int kt = 0; kt < 16; ++kt) {
    const long k0 = (long)kt << 6;
    __syncthreads();
#pragma unroll
    for (int i = 0; i < 2; ++i) {
      int r = 16 * wv + 8 * i + (lane >> 3);
      int gc = (lane & 7) ^ (r & 7);
      gl_lds16(A + (m0 + r) * 1024 + k0 + gc * 8, &As[16 * wv + 8 * i][0]);
    }
#pragma unroll
    for (int i = 0; i < 4; ++i) {
      int r = 32 * wv + 8 * i + (lane >> 3);
      int gc = (lane & 7) ^ (r & 7);
      gl_lds16(B + (n0 + r) * 1024 + k0 + gc * 8, &Bs[32 * wv + 8 * i][0]);
    }
    __syncthreads();
#pragma unroll
    for (int s = 0; s < 2; ++s) {
      f16x8 af[2], bfr[4];
#pragma unroll
      for (int mi = 0; mi < 2; ++mi) {
        int r = wm * 32 + mi * 16 + cc;
        af[mi] = *(const f16x8*)(AsB + r * 128 + ((s * 64 + 16 * g) ^ ((r & 7) << 4)));
      }
#pragma unroll
      for (int ni = 0; ni < 4; ++ni) {
        int r = wn * 64 + ni * 16 + cc;
        bfr[ni] = *(const f16x8*)(BsB + r * 128 + ((s * 64 + 16 * g) ^ ((r & 7) << 4)));
      }
#pragma unroll
      for (int mi = 0; mi < 2; ++mi)
#pragma unroll
        for (int ni = 0; ni < 4; ++ni)
          acc[mi][ni] = __builtin_amdgcn_mfma_f32_16x16x32_f16(af[mi], bfr[ni], acc[mi][ni], 0, 0, 0);
    }
  }

#pragma unroll
  for (int ni = 0; ni < 4; ++ni) {
    long col = n0 + wn * 64 + ni * 16 + cc;
    float bcol = bias[col];
#pragma unroll
    for (int mi = 0; mi < 2; ++mi) {
      long row0 = m0 + wm * 32 + mi * 16 + 4 * g;
#pragma unroll
      for (int rg = 0; rg < 4; ++rg) {
        long row = row0 + rg;
        float vv = (acc[mi][ni][rg] + bcol) * alpha;
        long idx = (((row & 3) * NHEAD + (col >> 7)) * (long)L_SEQ + (row >> 2)) * 128 +
                   (col & 127);
        dst[idx] = (_Float16)vv;
      }
    }
  }
}

// ---------------------------------------------------------------------------
// proj64 (R8, proven): 64x128 tile, all-f16 dual gl_lds staging. For voT.
// ---------------------------------------------------------------------------
__global__ __launch_bounds__(256) void proj64(
    const _Float16* __restrict__ Ap, long lda, long a_bs,
    const _Float16* __restrict__ Bp, long ldb, long b_bs,
    _Float16* __restrict__ Ch, long ldch, long ch_bs,
    const float* __restrict__ bias, int bias_row, float alpha, int K,
    int cmode, int ntiles)
{
  __shared__ __align__(16) _Float16 As[64][64];
  __shared__ __align__(16) _Float16 Bs[128][64];
  const int tid = threadIdx.x, lane = tid & 63, wv = tid >> 6;
  const int g = lane >> 4, cc = lane & 15;
  const int wm = wv >> 1, wn = wv & 1;
  const int fi = (int)blockIdx.x;
  const int by = fi / ntiles, nc = fi % ntiles;
  const long m0 = (long)by * 64;
  const long n0 = (long)nc * 128;
  const _Float16* A = Ap + (long)blockIdx.z * a_bs;
  const _Float16* B = Bp + (long)blockIdx.z * b_bs;
  const int NT = K >> 6;

  f32x4 acc[2][4] = {};
  char* AsB = (char*)&As[0][0];
  char* BsB = (char*)&Bs[0][0];

  for (int kt = 0; kt < NT; ++kt) {
    const long k0 = (long)kt << 6;
    __syncthreads();
#pragma unroll
    for (int i = 0; i < 2; ++i) {
      int r = 16 * wv + 8 * i + (lane >> 3);
      int gc = (lane & 7) ^ (r & 7);
      gl_lds16(A + (m0 + r) * lda + k0 + gc * 8, &As[16 * wv + 8 * i][0]);
    }
#pragma unroll
    for (int i = 0; i < 4; ++i) {
      int r = 32 * wv + 8 * i + (lane >> 3);
      int gc = (lane & 7) ^ (r & 7);
      gl_lds16(B + (n0 + r) * ldb + k0 + gc * 8, &Bs[32 * wv + 8 * i][0]);
    }
    __syncthreads();
#pragma unroll
    for (int s = 0; s < 2; ++s) {
      f16x8 af[2], bfr[4];
#pragma unroll
      for (int mi = 0; mi < 2; ++mi) {
        int r = wm * 32 + mi * 16 + cc;
        af[mi] = *(const f16x8*)(AsB + r * 128 + ((s * 64 + 16 * g) ^ ((r & 7) << 4)));
      }
#pragma unroll
      for (int ni = 0; ni < 4; ++ni) {
        int r = wn * 64 + ni * 16 + cc;
        bfr[ni] = *(const f16x8*)(BsB + r * 128 + ((s * 64 + 16 * g) ^ ((r & 7) << 4)));
      }
#pragma unroll
      for (int mi = 0; mi < 2; ++mi)
#pragma unroll
        for (int ni = 0; ni < 4; ++ni)
          acc[mi][ni] = __builtin_amdgcn_mfma_f32_16x16x32_f16(af[mi], bfr[ni], acc[mi][ni], 0, 0, 0);
    }
  }

  _Float16* Chp = Ch + (long)blockIdx.z * ch_bs;
#pragma unroll
  for (int ni = 0; ni < 4; ++ni) {
    long col = n0 + wn * 64 + ni * 16 + cc;
    float bcol = bias_row ? 0.0f : bias[col];
#pragma unroll
    for (int mi = 0; mi < 2; ++mi) {
      long row0 = m0 + wm * 32 + mi * 16 + 4 * g;
#pragma unroll
      for (int rg = 0; rg < 4; ++rg) {
        long row = row0 + rg;
        float b = bias_row ? bias[row] : bcol;
        float vv = (acc[mi][ni][rg] + b) * alpha;
        if (cmode == 1) {
          long idx = (((row & 3) * NHEAD + (col >> 7)) * (long)L_SEQ + (row >> 2)) * 128 +
                     (col & 127);
          Chp[idx] = (_Float16)vv;
        } else {
          Chp[row * ldch + col] = (_Float16)vv;
        }
      }
    }
  }
}

// ---------------------------------------------------------------------------
// out_gemm16 (R13): out = wm16 @ voT^T + bo, causal, dual gl_lds f16.
// ---------------------------------------------------------------------------
__global__ __launch_bounds__(256) void out_gemm16(
    const _Float16* __restrict__ wm16, const _Float16* __restrict__ voT,
    const float* __restrict__ bo, float* __restrict__ out)
{
  __shared__ __align__(16) _Float16 As[64][64];
  __shared__ __align__(16) _Float16 Bs[128][64];
  const int tid = threadIdx.x, lane = tid & 63, wv = tid >> 6;
  const int g = lane >> 4, cc = lane & 15;
  const int wm = wv >> 1, wn = wv & 1;
  const int fi = (int)blockIdx.x;
  const int by = 31 - (fi >> 5);
  const int j = fi & 31;
  const int nb = j >> 3, nc = j & 7;
  const long m0 = (long)by * 64;
  const long n0 = (long)nc * 128;
  const _Float16* A = wm16 + (long)nb * L_SEQ * L_SEQ;
  const _Float16* B = voT + (long)nb * 2048L * 1024;
  const int NT = by + 1;

  f32x4 acc[2][4] = {};
  char* AsB = (char*)&As[0][0];
  char* BsB = (char*)&Bs[0][0];

  for (int kt = 0; kt < NT; ++kt) {
    const long k0 = (long)kt << 6;
    __syncthreads();
#pragma unroll
    for (int i = 0; i < 2; ++i) {
      int r = 16 * wv + 8 * i + (lane >> 3);
      int gc = (lane & 7) ^ (r & 7);
      gl_lds16(A + (m0 + r) * 2048 + k0 + gc * 8, &As[16 * wv + 8 * i][0]);
    }
#pragma unroll
    for (int i = 0; i < 4; ++i) {
      int r = 32 * wv + 8 * i + (lane >> 3);
      int gc = (lane & 7) ^ (r & 7);
      gl_lds16(B + (n0 + r) * 2048 + k0 + gc * 8, &Bs[32 * wv + 8 * i][0]);
    }
    __syncthreads();
#pragma unroll
    for (int s = 0; s < 2; ++s) {
      f16x8 af[2], bfr[4];
#pragma unroll
      for (int mi = 0; mi < 2; ++mi) {
        int r = wm * 32 + mi * 16 + cc;
        af[mi] = *(const f16x8*)(AsB + r * 128 + ((s * 64 + 16 * g) ^ ((r & 7) << 4)));
      }
#pragma unroll
      for (int ni = 0; ni < 4; ++ni) {
        int r = wn * 64 + ni * 16 + cc;
        bfr[ni] = *(const f16x8*)(BsB + r * 128 + ((s * 64 + 16 * g) ^ ((r & 7) << 4)));
      }
#pragma unroll
      for (int mi = 0; mi < 2; ++mi)
#pragma unroll
        for (int ni = 0; ni < 4; ++ni)
          acc[mi][ni] = __builtin_amdgcn_mfma_f32_16x16x32_f16(af[mi], bfr[ni], acc[mi][ni], 0, 0, 0);
    }
  }

#pragma unroll
  for (int ni = 0; ni < 4; ++ni) {
    long col = n0 + wn * 64 + ni * 16 + cc;
    float b = bo[col];
#pragma unroll
    for (int mi = 0; mi < 2; ++mi) {
      long l0 = m0 + wm * 32 + mi * 16 + 4 * g;
#pragma unroll
      for (int rg = 0; rg < 4; ++rg)
        out[(l0 + rg) * 4096 + nb * 1024 + col] = acc[mi][ni][rg] + b;
    }
  }
}

// ---------------------------------------------------------------------------
// S1 (R10, proven): K-split partial Zsum via atomicAdd. 80-segment grid.
// ---------------------------------------------------------------------------
__global__ __launch_bounds__(256) void s1_kernel(
    const _Float16* __restrict__ qph, const _Float16* __restrict__ kph,
    float* __restrict__ Zsum)
{
  __shared__ __align__(16) _Float16 Qs[64][128];
  __shared__ __align__(16) _Float16 Ks[64][128];
  const int tid = threadIdx.x, lane = tid & 63, w = tid >> 6;
  const int g = lane >> 4, cc = lane & 15;
  const int h = blockIdx.y, nb = blockIdx.z;
  int fi = 79 - (int)blockIdx.x;
  int by, seg;
  if (fi < 8)       { by = fi;                  seg = 0; }
  else if (fi < 24) { int t = fi - 8;  by = 8  + (t >> 1); seg = t & 1; }
  else if (fi < 48) { int t = fi - 24; by = 16 + t / 3;    seg = t % 3; }
  else              { int t = fi - 48; by = 24 + (t >> 2); seg = t & 3; }
  const int lb = by * 64;
  const int c0 = seg * 8;
  const int cEnd = min(c0 + 8, by + 1);
  const int srow = lane >> 4, scl = lane & 15;
  const long hb = ((long)(nb * NHEAD + h)) * L_SEQ * 128;
  char* QsB = (char*)&Qs[0][0];
  char* KsB = (char*)&Ks[0][0];

#pragma unroll
  for (int i = 0; i < 4; ++i) {
    int r = 16 * w + 4 * i + srow;
    int gc = scl ^ (r & 7);
    gl_lds16(&qph[hb + (long)(lb + r) * 128 + gc * 8], &Qs[16 * w + 4 * i][0]);
  }
  auto stageK = [&](int ch) {
#pragma unroll
    for (int i = 0; i < 4; ++i) {
      int r = 16 * w + 4 * i + srow;
      int gc = scl ^ (r & 7);
      gl_lds16(&kph[hb + (long)(ch * 64 + r) * 128 + gc * 8], &Ks[16 * w + 4 * i][0]);
    }
  };
  stageK(c0);
  __syncthreads();

  f16x8 qf[4];
  {
    int r = 16 * w + cc;
#pragma unroll
    for (int s = 0; s < 4; ++s)
      qf[s] = *(const f16x8*)(QsB + r * 256 + ((64 * s + 16 * g) ^ ((r & 7) << 4)));
  }

  f32x4 zacc = {0.f, 0.f, 0.f, 0.f};
  const int l0 = lb + 16 * w + 4 * g;
  for (int ch = c0; ch < cEnd; ++ch) {
#pragma unroll
    for (int t = 0; t < 4; ++t) {
      int kr = 16 * t + cc;
      f32x4 acc = {0.f, 0.f, 0.f, 0.f};
#pragma unroll
      for (int s = 0; s < 4; ++s) {
        f16x8 kf = *(const f16x8*)(KsB + kr * 256 + ((64 * s + 16 * g) ^ ((kr & 7) << 4)));
        acc = __builtin_amdgcn_mfma_f32_16x16x32_f16(qf[s], kf, acc, 0, 0, 0);
      }
      int m = ch * 64 + 16 * t + cc;
#pragma unroll
      for (int rg = 0; rg < 4; ++rg) {
        float e = __expf(acc[rg]);
        zacc[rg] += (m <= l0 + rg) ? e : 0.f;
      }
    }
    if (ch + 1 < cEnd) {
      __syncthreads();
      stageK(ch + 1);
      __syncthreads();
    }
  }
#pragma unroll
  for (int rg = 0; rg < 4; ++rg) {
    float vv = zacc[rg];
    vv += __shfl_xor(vv, 1, 16);
    vv += __shfl_xor(vv, 2, 16);
    vv += __shfl_xor(vv, 4, 16);
    vv += __shfl_xor(vv, 8, 16);
    if (cc == 0)
      atomicAdd(&Zsum[((long)nb * NHEAD + h) * L_SEQ + l0 + rg], vv);
  }
}

// ---------------------------------------------------------------------------
__global__ __launch_bounds__(256) void zero_fill(float* __restrict__ wmean)
{
  int t = (int)blockIdx.x, nb = (int)blockIdx.y;
  int by = 0, rem = t;
  while (rem >= 15 - by) { rem -= 15 - by; ++by; }
  const int mc = by + 1 + rem;
  const int tr = threadIdx.x >> 1, th = threadIdx.x & 1;
  float4 z4 = {0.f, 0.f, 0.f, 0.f};
  float* p = wmean + (long)nb * L_SEQ * L_SEQ + (long)(by * 128 + tr) * L_SEQ +
             mc * 128 + th * 64;
#pragma unroll
  for (int j = 0; j < 16; ++j) ((float4*)p)[j] = z4;
}

// ---------------------------------------------------------------------------
// S2 (64l x 128m tiles): 272 tiles/batch heavy-first + XCD swizzle (272=8*34);
// Q 16KB + K 32KB + zl -> 3 blocks/CU; 32 MFMA/wave per head-iter between
// barriers (2x R13); mask when mb+127 > lb. Writes f32 wmean + f16 wm16.
// ---------------------------------------------------------------------------
__global__ __launch_bounds__(256) void s2_kernel(
    const _Float16* __restrict__ qph, const _Float16* __restrict__ kph,
    const float* __restrict__ Zsum, float* __restrict__ wmean,
    _Float16* __restrict__ wm16)
{
  __shared__ __align__(16) _Float16 Qs[64][128];    // 16 KB
  __shared__ __align__(16) _Float16 Ks[128][128];   // 32 KB
  __shared__ float zl[NHEAD][64];
  const int tid = threadIdx.x, lane = tid & 63, w = tid >> 6;
  const int g = lane >> 4, cc = lane & 15;
  const int nb = blockIdx.y;
  int b = (int)blockIdx.x;
  int bx = (b & 7) * 34 + (b >> 3);          // XCD swizzle (272 = 8*34)
  int rem = 271 - bx;                        // heavy (large-by) first
  int by = 0;
  while (rem >= (by >> 1) + 1) { rem -= (by >> 1) + 1; ++by; }
  const int mc = rem;                        // mc <= by/2
  const int lb = by * 64, mb = mc * 128;
  const bool diag = (mb + 127 > lb);
  const int srow = lane >> 4, scl = lane & 15;
  char* QsB = (char*)&Qs[0][0];
  char* KsB = (char*)&Ks[0][0];

  for (int i = tid; i < NHEAD * 64; i += 256)
    zl[i >> 6][i & 63] =
        1.0f / (8.0f * Zsum[((long)nb * NHEAD + (i >> 6)) * L_SEQ + lb + (i & 63)]);

  auto stage = [&](int h) {
    const long qb = ((long)(nb * NHEAD + h) * L_SEQ + lb) * 128;
    const long kb = ((long)(nb * NHEAD + h) * L_SEQ + mb) * 128;
#pragma unroll
    for (int i = 0; i < 4; ++i) {
      int r = 16 * w + 4 * i + srow;
      int gc = scl ^ (r & 7);
      gl_lds16(&qph[qb + (long)r * 128 + gc * 8], &Qs[16 * w + 4 * i][0]);
    }
#pragma unroll
    for (int i = 0; i < 8; ++i) {
      int r = 32 * w + 4 * i + srow;
      int gc = scl ^ (r & 7);
      gl_lds16(&kph[kb + (long)r * 128 + gc * 8], &Ks[32 * w + 4 * i][0]);
    }
  };
  stage(0);
  __syncthreads();

  f32x4 wacc[8] = {};
  const int l0 = lb + 16 * w + 4 * g;
  for (int h = 0; h < NHEAD; ++h) {
    f16x8 qf[4];
    int qr = 16 * w + cc;
#pragma unroll
    for (int s = 0; s < 4; ++s)
      qf[s] = *(const f16x8*)(QsB + qr * 256 + ((64 * s + 16 * g) ^ ((qr & 7) << 4)));
    f32x4 zv = *(const f32x4*)&zl[h][16 * w + 4 * g];
#pragma unroll
    for (int t = 0; t < 8; ++t) {
      int kr = 16 * t + cc;
      f32x4 acc = {0.f, 0.f, 0.f, 0.f};
#pragma unroll
      for (int s = 0; s < 4; ++s) {
        f16x8 kf = *(const f16x8*)(KsB + kr * 256 + ((64 * s + 16 * g) ^ ((kr & 7) << 4)));
        acc = __builtin_amdgcn_mfma_f32_16x16x32_f16(qf[s], kf, acc, 0, 0, 0);
      }
      int m = mb + 16 * t + cc;
#pragma unroll
      for (int rg = 0; rg < 4; ++rg) {
        float e = __expf(acc[rg]) * zv[rg];
        wacc[t][rg] += (!diag || m <= l0 + rg) ? e : 0.f;
      }
    }
    if (h + 1 < NHEAD) {
      __syncthreads();
      stage(h + 1);
      __syncthreads();
    }
  }
  float* wout = wmean + (long)nb * L_SEQ * L_SEQ;
  _Float16* w16 = wm16 + (long)nb * L_SEQ * L_SEQ;
#pragma unroll
  for (int t = 0; t < 8; ++t) {
    int m = mb + 16 * t + cc;
#pragma unroll
    for (int rg = 0; rg < 4; ++rg) {
      long idx = (long)(l0 + rg) * L_SEQ + m;
      wout[idx] = wacc[t][rg];
      w16[idx] = (_Float16)wacc[t][rg];
    }
  }
}

// ---------------------------------------------------------------------------
extern "C" void kernel_launch(void* const* d_in, const int* in_sizes, int n_in,
                              void* d_out, int out_size, void* d_ws, size_t ws_size,
                              hipStream_t stream)
{
  const float* q  = (const float*)d_in[0];
  const float* k  = (const float*)d_in[1];
  const float* v  = (const float*)d_in[2];
  const float* Wq = (const float*)d_in[3];
  const float* bq = (const float*)d_in[4];
  const float* Wk = (const float*)d_in[5];
  const float* bk = (const float*)d_in[6];
  const float* Wv = (const float*)d_in[7];
  const float* bv = (const float*)d_in[8];
  const float* Wo = (const float*)d_in[9];
  const float* bo = (const float*)d_in[10];

  float* out = (float*)d_out;
  float* wmean = out + (long)L_SEQ * NBATCH * DMODEL;

  if (ws_size < (140UL << 20)) return;

  char* ws = (char*)d_ws;
  _Float16* xh   = (_Float16*)(ws);                   // 48 MB (q,k,v f16)
  _Float16* qph  = (_Float16*)(ws + (48L << 20));     // 16 MB head-major
  _Float16* kph  = (_Float16*)(ws + (64L << 20));     // 16 MB head-major
  _Float16* voT  = (_Float16*)(ws + (80L << 20));     // 16 MB
  _Float16* wm16 = (_Float16*)(ws + (96L << 20));     // 33.6 MB (f16 wmean)
  _Float16* WqT  = (_Float16*)(ws + (130L << 20));    // 2 MB
  _Float16* WkT  = (_Float16*)(ws + (132L << 20));    // 2 MB
  _Float16* WoT  = (_Float16*)(ws + (134L << 20));    // 2 MB
  _Float16* WvoT = (_Float16*)(ws + (136L << 20));    // 2 MB
  float*    bvo  = (float*)   (ws + (138L << 20));    // 4 KB
  float*    Zsum = (float*)   (ws + (138L << 20) + (1L << 16));  // 256 KB

  // weight transposes + bias_proj + Zsum zero, one launch
  prep<<<dim3(32, 32, 4), dim3(32, 8, 1), 0, stream>>>(
      Wq, Wk, Wo, WqT, WkT, WoT, bv, bvo, (float4*)Zsum);
  gemm16<true, false><<<dim3(8, 8, 1), 256, 0, stream>>>(
      WoT, 1024, 0, Wv, 1024, 0,
      (float*)nullptr, 0, 0, WvoT, 1024, 0,
      (const float*)nullptr, 0, 1.0f, 1024, 0, 0);
  cvt3<<<dim3(12288, 1, 1), 256, 0, stream>>>(q, k, v, xh);
  projqk<<<dim3(1024, 2, 1), 256, 0, stream>>>(xh, WqT, WkT, bq, bk, qph, kph);
  proj64<<<dim3(256, 1, 4), 256, 0, stream>>>(
      WvoT, 1024, 0, xh + 2 * NQ, 4096, 1024, voT, 2048, 2048L * 1024,
      bvo, 1, 1.0f, 1024, 0, 16);
  s1_kernel<<<dim3(80, NHEAD, NBATCH), 256, 0, stream>>>(qph, kph, Zsum);
  zero_fill<<<dim3(120, 4, 1), 256, 0, stream>>>(wmean);
  s2_kernel<<<dim3(272, NBATCH, 1), 256, 0, stream>>>(qph, kph, Zsum, wmean, wm16);
  out_gemm16<<<dim3(1024, 1, 1), 256, 0, stream>>>(wm16, voT, bo, out);
}

// Round 15
// 314.461 us; speedup vs baseline: 1.1541x; 1.0002x over previous
//
#include <hip/hip_runtime.h>

// R15: BK=128 for out_gemm16 (serial chain 32->16 chunks, 32 MFMA/barrier,
// 48KB LDS/3 blocks/CU — same cure as s2's R14 win) and projqk (16->8 chunks).
// s2's masked-zero coverage provably covers all BK=128 causal reads of wm16.
// Rest = R14 (314.5us best).

#define L_SEQ 2048
#define NBATCH 4
#define DMODEL 1024
#define NHEAD 8
#define SCALING 0.08838834764831845f
#define NQ (2048L * 4 * 1024)

typedef _Float16 f16x8 __attribute__((ext_vector_type(8)));
typedef float f32x4 __attribute__((ext_vector_type(4)));

#define GLOBAL_AS __attribute__((address_space(1)))
#define LDS_AS __attribute__((address_space(3)))

__device__ __forceinline__ unsigned short f2h_bits(float x) {
  _Float16 h = (_Float16)x;
  return __builtin_bit_cast(unsigned short, h);
}

__device__ __forceinline__ void gl_lds16(const void* g, void* l) {
  __builtin_amdgcn_global_load_lds((GLOBAL_AS void*)g, (LDS_AS void*)l, 16, 0, 0);
}

// ---------------------------------------------------------------------------
// prep (R14): z<3 weight transposes; z==3 bias_proj + Zsum zero.
// ---------------------------------------------------------------------------
__global__ __launch_bounds__(256) void prep(
    const float* __restrict__ Wq, const float* __restrict__ Wk,
    const float* __restrict__ Wo,
    _Float16* __restrict__ WqT, _Float16* __restrict__ WkT,
    _Float16* __restrict__ WoT,
    const float* __restrict__ bv, float* __restrict__ bvo,
    float4* __restrict__ Zsum4)
{
  const int z = (int)blockIdx.z;
  const int tid = threadIdx.y * 32 + threadIdx.x;
  if (z == 3) {
    if (blockIdx.y == 0 && blockIdx.x < 4) {
      int j = blockIdx.x * 256 + tid;
      float acc = 0.f;
      for (int i = 0; i < DMODEL; ++i) acc += bv[i] * Wo[(long)i * DMODEL + j];
      bvo[j] = acc;
    } else if (blockIdx.y == 1 || blockIdx.y == 2) {
      long idx = ((long)(blockIdx.y - 1) * 32 + blockIdx.x) * 256 + tid;
      if (idx < (long)NBATCH * NHEAD * L_SEQ / 4)
        Zsum4[idx] = (float4){0.f, 0.f, 0.f, 0.f};
    }
    return;
  }
  __shared__ _Float16 tile[32][33];
  const float* in = z == 0 ? Wq : (z == 1 ? Wk : Wo);
  _Float16* outp = z == 0 ? WqT : (z == 1 ? WkT : WoT);
  int r0 = blockIdx.y * 32, c0 = blockIdx.x * 32;
  for (int i = threadIdx.y; i < 32; i += 8)
    tile[i][threadIdx.x] = (_Float16)in[(long)(r0 + i) * 1024 + c0 + threadIdx.x];
  __syncthreads();
  for (int i = threadIdx.y; i < 32; i += 8)
    outp[(long)(c0 + i) * 1024 + r0 + threadIdx.x] = tile[threadIdx.x][i];
}

// ---------------------------------------------------------------------------
__global__ __launch_bounds__(256) void cvt3(
    const float* __restrict__ q, const float* __restrict__ k,
    const float* __restrict__ v, _Float16* __restrict__ xh)
{
  long i = ((long)blockIdx.x * 256 + threadIdx.x) * 8;
  if (i >= 3 * NQ) return;
  int which = (int)(i / NQ);
  const float* src = which == 0 ? q : (which == 1 ? k : v);
  long off = i - (long)which * NQ;
  float4 a = *(const float4*)(src + off);
  float4 b = *(const float4*)(src + off + 4);
  f16x8 h;
  h[0] = (_Float16)a.x; h[1] = (_Float16)a.y; h[2] = (_Float16)a.z; h[3] = (_Float16)a.w;
  h[4] = (_Float16)b.x; h[5] = (_Float16)b.y; h[6] = (_Float16)b.z; h[7] = (_Float16)b.w;
  *(f16x8*)(xh + i) = h;
}

// ---------------------------------------------------------------------------
// gemm16: 128x128 tile. Retained for the small Wvo prep GEMM only.
// ---------------------------------------------------------------------------
template <bool AF16, bool BF16>
__global__ __launch_bounds__(256) void gemm16(
    const void* __restrict__ Ap, long lda, long a_bs,
    const void* __restrict__ Bp, long ldb, long b_bs,
    float* __restrict__ C, long ldc, long c_bs,
    _Float16* __restrict__ Ch, long ldch, long ch_bs,
    const float* __restrict__ bias, int bias_row, float alpha, int K,
    int causal, int cmode)
{
  __shared__ __align__(16) _Float16 As[128][64];
  __shared__ __align__(16) _Float16 Bs[128][64];
  const int tid = threadIdx.x;
  const int lane = tid & 63, wv = tid >> 6;
  const int g = lane >> 4, cc = lane & 15;
  const int wm = wv >> 1, wn = wv & 1;
  const long m0 = (long)blockIdx.y * 128;
  const long n0 = (long)blockIdx.x * 128;

  const float* Af = nullptr; const _Float16* Ah = nullptr;
  const float* Bf = nullptr; const _Float16* Bh = nullptr;
  if constexpr (AF16) Ah = (const _Float16*)Ap + (long)blockIdx.z * a_bs;
  else                Af = (const float*)Ap + (long)blockIdx.z * a_bs;
  if constexpr (BF16) Bh = (const _Float16*)Bp + (long)blockIdx.z * b_bs;
  else                Bf = (const float*)Bp + (long)blockIdx.z * b_bs;

  int Keff = K;
  if (causal) { int lim = (int)m0 + 128; if (lim < K) Keff = lim; }
  const int NT = Keff >> 6;

  f32x4 acc[4][4] = {};
  char* AsB = (char*)&As[0][0];
  char* BsB = (char*)&Bs[0][0];

  for (int kt = 0; kt < NT; ++kt) {
    const long k0 = (long)kt << 6;
    __syncthreads();
    if constexpr (AF16) {
#pragma unroll
      for (int i = 0; i < 4; ++i) {
        int r = 32 * wv + 8 * i + (lane >> 3);
        int gc = (lane & 7) ^ (r & 7);
        gl_lds16(Ah + (m0 + r) * lda + k0 + gc * 8, &As[32 * wv + 8 * i][0]);
      }
    } else {
#pragma unroll
      for (int p = 0; p < 8; ++p) {
        int r = p * 16 + (tid >> 4);
        float4 vv = *(const float4*)(Af + (m0 + r) * lda + k0 + (tid & 15) * 4);
        ushort4 hh;
        hh.x = f2h_bits(vv.x); hh.y = f2h_bits(vv.y);
        hh.z = f2h_bits(vv.z); hh.w = f2h_bits(vv.w);
        *(ushort4*)(AsB + r * 128 + (((tid & 15) * 8) ^ ((r & 7) << 4))) = hh;
      }
    }
    if constexpr (BF16) {
#pragma unroll
      for (int i = 0; i < 4; ++i) {
        int r = 32 * wv + 8 * i + (lane >> 3);
        int gc = (lane & 7) ^ (r & 7);
        gl_lds16(Bh + (n0 + r) * ldb + k0 + gc * 8, &Bs[32 * wv + 8 * i][0]);
      }
    } else {
#pragma unroll
      for (int p = 0; p < 8; ++p) {
        int r = p * 16 + (tid >> 4);
        float4 vv = *(const float4*)(Bf + (n0 + r) * ldb + k0 + (tid & 15) * 4);
        ushort4 hh;
        hh.x = f2h_bits(vv.x); hh.y = f2h_bits(vv.y);
        hh.z = f2h_bits(vv.z); hh.w = f2h_bits(vv.w);
        *(ushort4*)(BsB + r * 128 + (((tid & 15) * 8) ^ ((r & 7) << 4))) = hh;
      }
    }
    __syncthreads();
#pragma unroll
    for (int s = 0; s < 2; ++s) {
      f16x8 af[4], bfr[4];
#pragma unroll
      for (int mi = 0; mi < 4; ++mi) {
        int r = wm * 64 + mi * 16 + cc;
        af[mi] = *(const f16x8*)(AsB + r * 128 + ((s * 64 + 16 * g) ^ ((r & 7) << 4)));
      }
#pragma unroll
      for (int ni = 0; ni < 4; ++ni) {
        int r = wn * 64 + ni * 16 + cc;
        bfr[ni] = *(const f16x8*)(BsB + r * 128 + ((s * 64 + 16 * g) ^ ((r & 7) << 4)));
      }
#pragma unroll
      for (int mi = 0; mi < 4; ++mi)
#pragma unroll
        for (int ni = 0; ni < 4; ++ni)
          acc[mi][ni] = __builtin_amdgcn_mfma_f32_16x16x32_f16(af[mi], bfr[ni], acc[mi][ni], 0, 0, 0);
    }
  }

  float* Cp = C ? C + (long)blockIdx.z * c_bs : nullptr;
  _Float16* Chp = Ch ? Ch + (long)blockIdx.z * ch_bs : nullptr;
#pragma unroll
  for (int ni = 0; ni < 4; ++ni) {
    long col = n0 + wn * 64 + ni * 16 + cc;
    float bcol = (bias && !bias_row) ? bias[col] : 0.0f;
#pragma unroll
    for (int mi = 0; mi < 4; ++mi) {
      long row0 = m0 + wm * 64 + mi * 16 + 4 * g;
#pragma unroll
      for (int rg = 0; rg < 4; ++rg) {
        long row = row0 + rg;
        float b = (bias && bias_row) ? bias[row] : bcol;
        float vv = (acc[mi][ni][rg] + b) * alpha;
        if (Cp) Cp[row * ldc + col] = vv;
        if (Chp) {
          if (cmode == 1) {
            long idx = (((row & 3) * NHEAD + (col >> 7)) * (long)L_SEQ + (row >> 2)) * 128 +
                       (col & 127);
            Chp[idx] = (_Float16)vv;
          } else {
            Chp[row * ldch + col] = (_Float16)vv;
          }
        }
      }
    }
  }
}

// ---------------------------------------------------------------------------
// projqk (BK=128): q/k projections, 64x128 tile, 8 K-chunks of 128.
// As 64x128 (16KB) + Bs 128x128 (32KB) = 48KB, 3 blocks/CU, grid 2048.
// ---------------------------------------------------------------------------
__global__ __launch_bounds__(256) void projqk(
    const _Float16* __restrict__ xh, const _Float16* __restrict__ WqT,
    const _Float16* __restrict__ WkT, const float* __restrict__ bq,
    const float* __restrict__ bk, _Float16* __restrict__ qph,
    _Float16* __restrict__ kph)
{
  __shared__ __align__(16) _Float16 As[64][128];
  __shared__ __align__(16) _Float16 Bs[128][128];
  const int tid = threadIdx.x, lane = tid & 63, wv = tid >> 6;
  const int g = lane >> 4, cc = lane & 15;
  const int wm = wv >> 1, wn = wv & 1;
  const int sel = (int)blockIdx.y;
  const _Float16* A = xh + (long)sel * NQ;
  const _Float16* B = sel ? WkT : WqT;
  const float* bias = sel ? bk : bq;
  const float alpha = sel ? 1.0f : SCALING;
  _Float16* dst = sel ? kph : qph;
  const int fi = (int)blockIdx.x;
  const long m0 = (long)(fi >> 3) * 64;
  const long n0 = (long)(fi & 7) * 128;
  const int srow = lane >> 4, scl = lane & 15;

  f32x4 acc[2][4] = {};
  char* AsB = (char*)&As[0][0];
  char* BsB = (char*)&Bs[0][0];

  for (int kt = 0; kt < 8; ++kt) {
    const long k0 = (long)kt << 7;
    __syncthreads();
#pragma unroll
    for (int i = 0; i < 4; ++i) {          // A: 64 rows x 256B, 4 rows/instr
      int r = 16 * wv + 4 * i + srow;
      int gc = scl ^ (r & 7);
      gl_lds16(A + (m0 + r) * 1024 + k0 + gc * 8, &As[16 * wv + 4 * i][0]);
    }
#pragma unroll
    for (int i = 0; i < 8; ++i) {          // B: 128 rows x 256B
      int r = 32 * wv + 4 * i + srow;
      int gc = scl ^ (r & 7);
      gl_lds16(B + (n0 + r) * 1024 + k0 + gc * 8, &Bs[32 * wv + 4 * i][0]);
    }
    __syncthreads();
#pragma unroll
    for (int s = 0; s < 4; ++s) {
      f16x8 af[2], bfr[4];
#pragma unroll
      for (int mi = 0; mi < 2; ++mi) {
        int r = wm * 32 + mi * 16 + cc;
        af[mi] = *(const f16x8*)(AsB + r * 256 + (((4 * s + g) ^ (r & 7)) << 4));
      }
#pragma unroll
      for (int ni = 0; ni < 4; ++ni) {
        int r = wn * 64 + ni * 16 + cc;
        bfr[ni] = *(const f16x8*)(BsB + r * 256 + (((4 * s + g) ^ (r & 7)) << 4));
      }
#pragma unroll
      for (int mi = 0; mi < 2; ++mi)
#pragma unroll
        for (int ni = 0; ni < 4; ++ni)
          acc[mi][ni] = __builtin_amdgcn_mfma_f32_16x16x32_f16(af[mi], bfr[ni], acc[mi][ni], 0, 0, 0);
    }
  }

#pragma unroll
  for (int ni = 0; ni < 4; ++ni) {
    long col = n0 + wn * 64 + ni * 16 + cc;
    float bcol = bias[col];
#pragma unroll
    for (int mi = 0; mi < 2; ++mi) {
      long row0 = m0 + wm * 32 + mi * 16 + 4 * g;
#pragma unroll
      for (int rg = 0; rg < 4; ++rg) {
        long row = row0 + rg;
        float vv = (acc[mi][ni][rg] + bcol) * alpha;
        long idx = (((row & 3) * NHEAD + (col >> 7)) * (long)L_SEQ + (row >> 2)) * 128 +
                   (col & 127);
        dst[idx] = (_Float16)vv;
      }
    }
  }
}

// ---------------------------------------------------------------------------
// proj64 (R8, proven): 64x128 tile, BK=64 dual gl_lds staging. For voT.
// ---------------------------------------------------------------------------
__global__ __launch_bounds__(256) void proj64(
    const _Float16* __restrict__ Ap, long lda, long a_bs,
    const _Float16* __restrict__ Bp, long ldb, long b_bs,
    _Float16* __restrict__ Ch, long ldch, long ch_bs,
    const float* __restrict__ bias, int bias_row, float alpha, int K,
    int cmode, int ntiles)
{
  __shared__ __align__(16) _Float16 As[64][64];
  __shared__ __align__(16) _Float16 Bs[128][64];
  const int tid = threadIdx.x, lane = tid & 63, wv = tid >> 6;
  const int g = lane >> 4, cc = lane & 15;
  const int wm = wv >> 1, wn = wv & 1;
  const int fi = (int)blockIdx.x;
  const int by = fi / ntiles, nc = fi % ntiles;
  const long m0 = (long)by * 64;
  const long n0 = (long)nc * 128;
  const _Float16* A = Ap + (long)blockIdx.z * a_bs;
  const _Float16* B = Bp + (long)blockIdx.z * b_bs;
  const int NT = K >> 6;

  f32x4 acc[2][4] = {};
  char* AsB = (char*)&As[0][0];
  char* BsB = (char*)&Bs[0][0];

  for (int kt = 0; kt < NT; ++kt) {
    const long k0 = (long)kt << 6;
    __syncthreads();
#pragma unroll
    for (int i = 0; i < 2; ++i) {
      int r = 16 * wv + 8 * i + (lane >> 3);
      int gc = (lane & 7) ^ (r & 7);
      gl_lds16(A + (m0 + r) * lda + k0 + gc * 8, &As[16 * wv + 8 * i][0]);
    }
#pragma unroll
    for (int i = 0; i < 4; ++i) {
      int r = 32 * wv + 8 * i + (lane >> 3);
      int gc = (lane & 7) ^ (r & 7);
      gl_lds16(B + (n0 + r) * ldb + k0 + gc * 8, &Bs[32 * wv + 8 * i][0]);
    }
    __syncthreads();
#pragma unroll
    for (int s = 0; s < 2; ++s) {
      f16x8 af[2], bfr[4];
#pragma unroll
      for (int mi = 0; mi < 2; ++mi) {
        int r = wm * 32 + mi * 16 + cc;
        af[mi] = *(const f16x8*)(AsB + r * 128 + ((s * 64 + 16 * g) ^ ((r & 7) << 4)));
      }
#pragma unroll
      for (int ni = 0; ni < 4; ++ni) {
        int r = wn * 64 + ni * 16 + cc;
        bfr[ni] = *(const f16x8*)(BsB + r * 128 + ((s * 64 + 16 * g) ^ ((r & 7) << 4)));
      }
#pragma unroll
      for (int mi = 0; mi < 2; ++mi)
#pragma unroll
        for (int ni = 0; ni < 4; ++ni)
          acc[mi][ni] = __builtin_amdgcn_mfma_f32_16x16x32_f16(af[mi], bfr[ni], acc[mi][ni], 0, 0, 0);
    }
  }

  _Float16* Chp = Ch + (long)blockIdx.z * ch_bs;
#pragma unroll
  for (int ni = 0; ni < 4; ++ni) {
    long col = n0 + wn * 64 + ni * 16 + cc;
    float bcol = bias_row ? 0.0f : bias[col];
#pragma unroll
    for (int mi = 0; mi < 2; ++mi) {
      long row0 = m0 + wm * 32 + mi * 16 + 4 * g;
#pragma unroll
      for (int rg = 0; rg < 4; ++rg) {
        long row = row0 + rg;
        float b = bias_row ? bias[row] : bcol;
        float vv = (acc[mi][ni][rg] + b) * alpha;
        if (cmode == 1) {
          long idx = (((row & 3) * NHEAD + (col >> 7)) * (long)L_SEQ + (row >> 2)) * 128 +
                     (col & 127);
          Chp[idx] = (_Float16)vv;
        } else {
          Chp[row * ldch + col] = (_Float16)vv;
        }
      }
    }
  }
}

// ---------------------------------------------------------------------------
// out_gemm16 (BK=128): out = wm16 @ voT^T + bo, causal. Serial chain halved:
// NT=(by+2)>>1 chunks of 128, 32 MFMA/wave per barrier. 48KB LDS, 3/CU,
// 1024 blocks heavy-first (now with backfill). s2's masked-zero coverage
// includes every column this reads (m < ((by>>1)+1)*128).
// ---------------------------------------------------------------------------
__global__ __launch_bounds__(256) void out_gemm16(
    const _Float16* __restrict__ wm16, const _Float16* __restrict__ voT,
    const float* __restrict__ bo, float* __restrict__ out)
{
  __shared__ __align__(16) _Float16 As[64][128];   // 16 KB
  __shared__ __align__(16) _Float16 Bs[128][128];  // 32 KB
  const int tid = threadIdx.x, lane = tid & 63, wv = tid >> 6;
  const int g = lane >> 4, cc = lane & 15;
  const int wm = wv >> 1, wn = wv & 1;
  const int fi = (int)blockIdx.x;
  const int by = 31 - (fi >> 5);            // heavy (long-K) blocks first
  const int j = fi & 31;
  const int nb = j >> 3, nc = j & 7;
  const long m0 = (long)by * 64;
  const long n0 = (long)nc * 128;
  const _Float16* A = wm16 + (long)nb * L_SEQ * L_SEQ;
  const _Float16* B = voT + (long)nb * 2048L * 1024;
  const int NT = (by + 2) >> 1;
  const int srow = lane >> 4, scl = lane & 15;

  f32x4 acc[2][4] = {};
  char* AsB = (char*)&As[0][0];
  char* BsB = (char*)&Bs[0][0];

  for (int kt = 0; kt < NT; ++kt) {
    const long k0 = (long)kt << 7;
    __syncthreads();
#pragma unroll
    for (int i = 0; i < 4; ++i) {          // A: 64 rows x 256B
      int r = 16 * wv + 4 * i + srow;
      int gc = scl ^ (r & 7);
      gl_lds16(A + (m0 + r) * 2048 + k0 + gc * 8, &As[16 * wv + 4 * i][0]);
    }
#pragma unroll
    for (int i = 0; i < 8; ++i) {          // B: 128 rows x 256B
      int r = 32 * wv + 4 * i + srow;
      int gc = scl ^ (r & 7);
      gl_lds16(B + (n0 + r) * 2048 + k0 + gc * 8, &Bs[32 * wv + 4 * i][0]);
    }
    __syncthreads();
#pragma unroll
    for (int s = 0; s < 4; ++s) {
      f16x8 af[2], bfr[4];
#pragma unroll
      for (int mi = 0; mi < 2; ++mi) {
        int r = wm * 32 + mi * 16 + cc;
        af[mi] = *(const f16x8*)(AsB + r * 256 + (((4 * s + g) ^ (r & 7)) << 4));
      }
#pragma unroll
      for (int ni = 0; ni < 4; ++ni) {
        int r = wn * 64 + ni * 16 + cc;
        bfr[ni] = *(const f16x8*)(BsB + r * 256 + (((4 * s + g) ^ (r & 7)) << 4));
      }
#pragma unroll
      for (int mi = 0; mi < 2; ++mi)
#pragma unroll
        for (int ni = 0; ni < 4; ++ni)
          acc[mi][ni] = __builtin_amdgcn_mfma_f32_16x16x32_f16(af[mi], bfr[ni], acc[mi][ni], 0, 0, 0);
    }
  }

#pragma unroll
  for (int ni = 0; ni < 4; ++ni) {
    long col = n0 + wn * 64 + ni * 16 + cc;
    float b = bo[col];
#pragma unroll
    for (int mi = 0; mi < 2; ++mi) {
      long l0 = m0 + wm * 32 + mi * 16 + 4 * g;
#pragma unroll
      for (int rg = 0; rg < 4; ++rg)
        out[(l0 + rg) * 4096 + nb * 1024 + col] = acc[mi][ni][rg] + b;
    }
  }
}

// ---------------------------------------------------------------------------
// S1 (R10, proven): K-split partial Zsum via atomicAdd. 80-segment grid.
// ---------------------------------------------------------------------------
__global__ __launch_bounds__(256) void s1_kernel(
    const _Float16* __restrict__ qph, const _Float16* __restrict__ kph,
    float* __restrict__ Zsum)
{
  __shared__ __align__(16) _Float16 Qs[64][128];
  __shared__ __align__(16) _Float16 Ks[64][128];
  const int tid = threadIdx.x, lane = tid & 63, w = tid >> 6;
  const int g = lane >> 4, cc = lane & 15;
  const int h = blockIdx.y, nb = blockIdx.z;
  int fi = 79 - (int)blockIdx.x;
  int by, seg;
  if (fi < 8)       { by = fi;                  seg = 0; }
  else if (fi < 24) { int t = fi - 8;  by = 8  + (t >> 1); seg = t & 1; }
  else if (fi < 48) { int t = fi - 24; by = 16 + t / 3;    seg = t % 3; }
  else              { int t = fi - 48; by = 24 + (t >> 2); seg = t & 3; }
  const int lb = by * 64;
  const int c0 = seg * 8;
  const int cEnd = min(c0 + 8, by + 1);
  const int srow = lane >> 4, scl = lane & 15;
  const long hb = ((long)(nb * NHEAD + h)) * L_SEQ * 128;
  char* QsB = (char*)&Qs[0][0];
  char* KsB = (char*)&Ks[0][0];

#pragma unroll
  for (int i = 0; i < 4; ++i) {
    int r = 16 * w + 4 * i + srow;
    int gc = scl ^ (r & 7);
    gl_lds16(&qph[hb + (long)(lb + r) * 128 + gc * 8], &Qs[16 * w + 4 * i][0]);
  }
  auto stageK = [&](int ch) {
#pragma unroll
    for (int i = 0; i < 4; ++i) {
      int r = 16 * w + 4 * i + srow;
      int gc = scl ^ (r & 7);
      gl_lds16(&kph[hb + (long)(ch * 64 + r) * 128 + gc * 8], &Ks[16 * w + 4 * i][0]);
    }
  };
  stageK(c0);
  __syncthreads();

  f16x8 qf[4];
  {
    int r = 16 * w + cc;
#pragma unroll
    for (int s = 0; s < 4; ++s)
      qf[s] = *(const f16x8*)(QsB + r * 256 + ((64 * s + 16 * g) ^ ((r & 7) << 4)));
  }

  f32x4 zacc = {0.f, 0.f, 0.f, 0.f};
  const int l0 = lb + 16 * w + 4 * g;
  for (int ch = c0; ch < cEnd; ++ch) {
#pragma unroll
    for (int t = 0; t < 4; ++t) {
      int kr = 16 * t + cc;
      f32x4 acc = {0.f, 0.f, 0.f, 0.f};
#pragma unroll
      for (int s = 0; s < 4; ++s) {
        f16x8 kf = *(const f16x8*)(KsB + kr * 256 + ((64 * s + 16 * g) ^ ((kr & 7) << 4)));
        acc = __builtin_amdgcn_mfma_f32_16x16x32_f16(qf[s], kf, acc, 0, 0, 0);
      }
      int m = ch * 64 + 16 * t + cc;
#pragma unroll
      for (int rg = 0; rg < 4; ++rg) {
        float e = __expf(acc[rg]);
        zacc[rg] += (m <= l0 + rg) ? e : 0.f;
      }
    }
    if (ch + 1 < cEnd) {
      __syncthreads();
      stageK(ch + 1);
      __syncthreads();
    }
  }
#pragma unroll
  for (int rg = 0; rg < 4; ++rg) {
    float vv = zacc[rg];
    vv += __shfl_xor(vv, 1, 16);
    vv += __shfl_xor(vv, 2, 16);
    vv += __shfl_xor(vv, 4, 16);
    vv += __shfl_xor(vv, 8, 16);
    if (cc == 0)
      atomicAdd(&Zsum[((long)nb * NHEAD + h) * L_SEQ + l0 + rg], vv);
  }
}

// ---------------------------------------------------------------------------
__global__ __launch_bounds__(256) void zero_fill(float* __restrict__ wmean)
{
  int t = (int)blockIdx.x, nb = (int)blockIdx.y;
  int by = 0, rem = t;
  while (rem >= 15 - by) { rem -= 15 - by; ++by; }
  const int mc = by + 1 + rem;
  const int tr = threadIdx.x >> 1, th = threadIdx.x & 1;
  float4 z4 = {0.f, 0.f, 0.f, 0.f};
  float* p = wmean + (long)nb * L_SEQ * L_SEQ + (long)(by * 128 + tr) * L_SEQ +
             mc * 128 + th * 64;
#pragma unroll
  for (int j = 0; j < 16; ++j) ((float4*)p)[j] = z4;
}

// ---------------------------------------------------------------------------
// S2 (R14, proven): 64l x 128m tiles, 272/batch heavy-first + XCD swizzle.
// ---------------------------------------------------------------------------
__global__ __launch_bounds__(256) void s2_kernel(
    const _Float16* __restrict__ qph, const _Float16* __restrict__ kph,
    const float* __restrict__ Zsum, float* __restrict__ wmean,
    _Float16* __restrict__ wm16)
{
  __shared__ __align__(16) _Float16 Qs[64][128];
  __shared__ __align__(16) _Float16 Ks[128][128];
  __shared__ float zl[NHEAD][64];
  const int tid = threadIdx.x, lane = tid & 63, w = tid >> 6;
  const int g = lane >> 4, cc = lane & 15;
  const int nb = blockIdx.y;
  int b = (int)blockIdx.x;
  int bx = (b & 7) * 34 + (b >> 3);          // XCD swizzle (272 = 8*34)
  int rem = 271 - bx;                        // heavy (large-by) first
  int by = 0;
  while (rem >= (by >> 1) + 1) { rem -= (by >> 1) + 1; ++by; }
  const int mc = rem;
  const int lb = by * 64, mb = mc * 128;
  const bool diag = (mb + 127 > lb);
  const int srow = lane >> 4, scl = lane & 15;
  char* QsB = (char*)&Qs[0][0];
  char* KsB = (char*)&Ks[0][0];

  for (int i = tid; i < NHEAD * 64; i += 256)
    zl[i >> 6][i & 63] =
        1.0f / (8.0f * Zsum[((long)nb * NHEAD + (i >> 6)) * L_SEQ + lb + (i & 63)]);

  auto stage = [&](int h) {
    const long qb = ((long)(nb * NHEAD + h) * L_SEQ + lb) * 128;
    const long kb = ((long)(nb * NHEAD + h) * L_SEQ + mb) * 128;
#pragma unroll
    for (int i = 0; i < 4; ++i) {
      int r = 16 * w + 4 * i + srow;
      int gc = scl ^ (r & 7);
      gl_lds16(&qph[qb + (long)r * 128 + gc * 8], &Qs[16 * w + 4 * i][0]);
    }
#pragma unroll
    for (int i = 0; i < 8; ++i) {
      int r = 32 * w + 4 * i + srow;
      int gc = scl ^ (r & 7);
      gl_lds16(&kph[kb + (long)r * 128 + gc * 8], &Ks[32 * w + 4 * i][0]);
    }
  };
  stage(0);
  __syncthreads();

  f32x4 wacc[8] = {};
  const int l0 = lb + 16 * w + 4 * g;
  for (int h = 0; h < NHEAD; ++h) {
    f16x8 qf[4];
    int qr = 16 * w + cc;
#pragma unroll
    for (int s = 0; s < 4; ++s)
      qf[s] = *(const f16x8*)(QsB + qr * 256 + ((64 * s + 16 * g) ^ ((qr & 7) << 4)));
    f32x4 zv = *(const f32x4*)&zl[h][16 * w + 4 * g];
#pragma unroll
    for (int t = 0; t < 8; ++t) {
      int kr = 16 * t + cc;
      f32x4 acc = {0.f, 0.f, 0.f, 0.f};
#pragma unroll
      for (int s = 0; s < 4; ++s) {
        f16x8 kf = *(const f16x8*)(KsB + kr * 256 + ((64 * s + 16 * g) ^ ((kr & 7) << 4)));
        acc = __builtin_amdgcn_mfma_f32_16x16x32_f16(qf[s], kf, acc, 0, 0, 0);
      }
      int m = mb + 16 * t + cc;
#pragma unroll
      for (int rg = 0; rg < 4; ++rg) {
        float e = __expf(acc[rg]) * zv[rg];
        wacc[t][rg] += (!diag || m <= l0 + rg) ? e : 0.f;
      }
    }
    if (h + 1 < NHEAD) {
      __syncthreads();
      stage(h + 1);
      __syncthreads();
    }
  }
  float* wout = wmean + (long)nb * L_SEQ * L_SEQ;
  _Float16* w16 = wm16 + (long)nb * L_SEQ * L_SEQ;
#pragma unroll
  for (int t = 0; t < 8; ++t) {
    int m = mb + 16 * t + cc;
#pragma unroll
    for (int rg = 0; rg < 4; ++rg) {
      long idx = (long)(l0 + rg) * L_SEQ + m;
      wout[idx] = wacc[t][rg];
      w16[idx] = (_Float16)wacc[t][rg];
    }
  }
}

// ---------------------------------------------------------------------------
extern "C" void kernel_launch(void* const* d_in, const int* in_sizes, int n_in,
                              void* d_out, int out_size, void* d_ws, size_t ws_size,
                              hipStream_t stream)
{
  const float* q  = (const float*)d_in[0];
  const float* k  = (const float*)d_in[1];
  const float* v  = (const float*)d_in[2];
  const float* Wq = (const float*)d_in[3];
  const float* bq = (const float*)d_in[4];
  const float* Wk = (const float*)d_in[5];
  const float* bk = (const float*)d_in[6];
  const float* Wv = (const float*)d_in[7];
  const float* bv = (const float*)d_in[8];
  const float* Wo = (const float*)d_in[9];
  const float* bo = (const float*)d_in[10];

  float* out = (float*)d_out;
  float* wmean = out + (long)L_SEQ * NBATCH * DMODEL;

  if (ws_size < (140UL << 20)) return;

  char* ws = (char*)d_ws;
  _Float16* xh   = (_Float16*)(ws);                   // 48 MB (q,k,v f16)
  _Float16* qph  = (_Float16*)(ws + (48L << 20));     // 16 MB head-major
  _Float16* kph  = (_Float16*)(ws + (64L << 20));     // 16 MB head-major
  _Float16* voT  = (_Float16*)(ws + (80L << 20));     // 16 MB
  _Float16* wm16 = (_Float16*)(ws + (96L << 20));     // 33.6 MB (f16 wmean)
  _Float16* WqT  = (_Float16*)(ws + (130L << 20));    // 2 MB
  _Float16* WkT  = (_Float16*)(ws + (132L << 20));    // 2 MB
  _Float16* WoT  = (_Float16*)(ws + (134L << 20));    // 2 MB
  _Float16* WvoT = (_Float16*)(ws + (136L << 20));    // 2 MB
  float*    bvo  = (float*)   (ws + (138L << 20));    // 4 KB
  float*    Zsum = (float*)   (ws + (138L << 20) + (1L << 16));  // 256 KB

  prep<<<dim3(32, 32, 4), dim3(32, 8, 1), 0, stream>>>(
      Wq, Wk, Wo, WqT, WkT, WoT, bv, bvo, (float4*)Zsum);
  gemm16<true, false><<<dim3(8, 8, 1), 256, 0, stream>>>(
      WoT, 1024, 0, Wv, 1024, 0,
      (float*)nullptr, 0, 0, WvoT, 1024, 0,
      (const float*)nullptr, 0, 1.0f, 1024, 0, 0);
  cvt3<<<dim3(12288, 1, 1), 256, 0, stream>>>(q, k, v, xh);
  projqk<<<dim3(1024, 2, 1), 256, 0, stream>>>(xh, WqT, WkT, bq, bk, qph, kph);
  proj64<<<dim3(256, 1, 4), 256, 0, stream>>>(
      WvoT, 1024, 0, xh + 2 * NQ, 4096, 1024, voT, 2048, 2048L * 1024,
      bvo, 1, 1.0f, 1024, 0, 16);
  s1_kernel<<<dim3(80, NHEAD, NBATCH), 256, 0, stream>>>(qph, kph, Zsum);
  zero_fill<<<dim3(120, 4, 1), 256, 0, stream>>>(wmean);
  s2_kernel<<<dim3(272, NBATCH, 1), 256, 0, stream>>>(qph, kph, Zsum, wmean, wm16);
  out_gemm16<<<dim3(1024, 1, 1), 256, 0, stream>>>(wm16, voT, bo, out);
}